// Round 7
// baseline (25640.656 us; speedup 1.0000x reference)
//
#include <hip/hip_runtime.h>
#include <hip/hip_bf16.h>

// ---------------- problem constants ----------------
#define TS 128
#define NB 256
#define HD 2048
#define H3 6144
#define LD 256
#define ED 1024
#define AD 32
#define FD 200
#define KE 288     // L + A
#define KQ 3072    // H + E
#define KR 2304    // L + H
#define MT 32768   // NB * TS

typedef __attribute__((ext_vector_type(8))) short short8;
typedef __attribute__((ext_vector_type(4))) float f32x4;

// ---------------- workspace layout (r2-identical) ----------------
constexpr size_t alup(size_t x) { return (x + 255) & ~size_t(255); }
constexpr size_t O_WE   = 0;
constexpr size_t O_WIH  = alup(O_WE   + 2ull*2048*288);
constexpr size_t O_WHH  = alup(O_WIH  + 2ull*6144*2048);
constexpr size_t O_WQ1  = alup(O_WHH  + 2ull*6144*2048);
constexpr size_t O_WQ2  = alup(O_WQ1  + 2ull*200*3072);
constexpr size_t O_WQMS = alup(O_WQ2  + 2ull*200*200);   // interleaved [qm0,qs0,...] rows
constexpr size_t O_WP1  = alup(O_WQMS + 2ull*512*200);
constexpr size_t O_WP2  = alup(O_WP1  + 2ull*200*2048);
constexpr size_t O_WPMS = alup(O_WP2  + 2ull*200*200);
constexpr size_t O_WR1  = alup(O_WPMS + 2ull*512*200);
constexpr size_t O_WR2  = alup(O_WR1  + 2ull*200*2304);
constexpr size_t O_WR3  = alup(O_WR2  + 2ull*200*200);
constexpr size_t O_BQMS = alup(O_WR3  + 2ull*200);       // f32[512] interleaved bias
constexpr size_t O_BPMS = alup(O_BQMS + 4ull*512);
constexpr size_t O_POSTB= alup(O_BPMS + 4ull*512);       // bf16 [256][256]
constexpr size_t O_HBF  = alup(O_POSTB+ 2ull*NB*LD);     // bf16 [256][2048]
constexpr size_t O_HF   = alup(O_HBF  + 2ull*NB*HD);     // f32  [256][2048]
constexpr size_t O_EMB  = alup(O_HF   + 4ull*NB*HD);     // bf16 [256][2048]
constexpr size_t O_GH   = alup(O_EMB  + 2ull*NB*HD);     // f32  [256][6144]
constexpr size_t O_Q1P  = alup(O_GH   + 4ull*NB*H3);     // f32  [4][256][256] split-K partials
constexpr size_t O_Q2   = alup(O_Q1P  + 4ull*16*NB*256);
constexpr size_t O_BARF = alup(O_Q2   + 2ull*NB*FD);
constexpr size_t O_BARC = alup(O_BARF + 4ull*(64*32+64));
constexpr size_t O_P1B  = alup(O_BARC + 4ull*(16*32+64));// bf16 [32768][200]
constexpr size_t O_P2B  = alup(O_P1B  + 2ull*(size_t)MT*FD);
constexpr size_t O_END  = alup(O_P2B  + 2ull*(size_t)MT*FD); // ~96.6 MB

// output offsets (f32 elements)
#define Y0 0ull
#define Y1 8388608ull
#define Y2 16777216ull
#define Y3 83886080ull
#define Y4 92274688ull
#define Y5 100663296ull
#define Y6 109051904ull
#define Y7 117440512ull

// ---------------- small helpers ----------------
__device__ __forceinline__ unsigned short f2bf(float f) {
  union { float f; unsigned u; } v; v.f = f;
  unsigned r = v.u + 0x7fffu + ((v.u >> 16) & 1u);
  return (unsigned short)(r >> 16);
}
__device__ __forceinline__ float bf2f(unsigned short u) {
  union { unsigned u; float f; } v; v.u = ((unsigned)u) << 16;
  return v.f;
}
__device__ __forceinline__ float sigm(float x) { return 1.f / (1.f + __expf(-x)); }
__device__ __forceinline__ float tanh_f(float x) {
  float e = __expf(-2.f * fabsf(x));
  float t = (1.f - e) / (1.f + e);
  return x >= 0.f ? t : -t;
}
__device__ __forceinline__ float softp(float x) { return x > 15.f ? x : log1pf(__expf(x)); }
__device__ __forceinline__ f32x4 z4() { f32x4 z; z[0]=0.f; z[1]=0.f; z[2]=0.f; z[3]=0.f; return z; }

struct SMem {
  alignas(16) short As[64*72];   // legacy reg-staged path
  alignas(16) short Ws[128*72];
};
struct SMemP {                   // pipelined gload_lds path: linear, double-buffered
  alignas(16) short A[2][64*64];
  alignas(16) short W[2][64*64];
};
union SMemU { SMemP p; SMem legacy; };
struct SMemQH {                  // k_tail: legacy bufs + resident q2 band
  alignas(16) short As[64*72];
  alignas(16) short Ws[128*72];
  alignas(16) short q2l[64*264]; // 64-row band, pad 264
};

struct Aseg {  // A operand: up to 2 concatenated segments, each f32 or bf16
  const char* p0; int lda0; int K0; int f0;
  const char* p1; int lda1; int f1;
  int K;
};

// ---------------- legacy reg-staged path (r1/r2-verified) ----------------
__device__ __forceinline__ void stageA(short* As, const Aseg& a, int m0, int k0) {
  const int t = threadIdx.x;
  const int row = t >> 2;
  const int cb = (t & 3) << 4;
  #pragma unroll
  for (int i = 0; i < 2; ++i) {
    const int c = cb + i * 8;
    const int gk = k0 + c;
    short8 v = {};
    if (gk < a.K) {
      const char* p; long idx; int isf;
      if (gk < a.K0) { p = a.p0; idx = (long)(m0 + row) * a.lda0 + gk; isf = a.f0; }
      else           { p = a.p1; idx = (long)(m0 + row) * a.lda1 + (gk - a.K0); isf = a.f1; }
      if (isf) {
        const float* pf = (const float*)p + idx;
        #pragma unroll
        for (int j = 0; j < 8; ++j) v[j] = (short)f2bf(pf[j]);
      } else {
        v = *(const short8*)((const short*)p + idx);
      }
    }
    *(short8*)&As[row*72 + c] = v;
  }
}

__device__ __forceinline__ void stageW(short* Ws, const short* W, int ldw, int n0, int BN,
                                       int Nmax, int k0, int K) {
  const int nch = BN << 3;
  for (int id = threadIdx.x; id < nch; id += 256) {
    const int row = id >> 3;
    const int c = (id & 7) << 3;
    const int gk = k0 + c;
    int gr = n0 + row; gr = gr < Nmax ? gr : Nmax - 1;
    short8 v = {};
    if (gk < K) v = *(const short8*)(W + (long)gr * ldw + gk);
    *(short8*)&Ws[row*72 + c] = v;
  }
}

// q2 A-stage: A = relu(sum_s q1_partial[s] + bq1), K=200, 4 slices (r3-verified)
__device__ __forceinline__ void stageA_red4(short* As, const float* q1p, const float* bq1,
                                            int m0, int k0) {
  const int t = threadIdx.x;
  const int row = t >> 2;
  const int cb = (t & 3) << 4;
  #pragma unroll
  for (int i = 0; i < 2; ++i) {
    const int c = cb + i * 8;
    const int gk = k0 + c;
    short8 v = {};
    if (gk < FD) {
      float s[8];
      #pragma unroll
      for (int j = 0; j < 8; ++j) s[j] = bq1[gk + j];
      #pragma unroll
      for (int ss = 0; ss < 4; ++ss) {
        const float* p = q1p + (size_t)ss * NB * 256 + (size_t)(m0 + row) * 256 + gk;
        #pragma unroll
        for (int j = 0; j < 8; ++j) s[j] += p[j];
      }
      #pragma unroll
      for (int j = 0; j < 8; ++j) v[j] = (short)f2bf(fmaxf(s[j], 0.f));
    }
    *(short8*)&As[row*72 + c] = v;
  }
}

template<int NF>
__device__ __forceinline__ void mma_tile(const short* As, const short* Ws, f32x4 acc[2][NF]) {
  const int lane = threadIdx.x & 63;
  const int w = threadIdx.x >> 6;
  const int wm = (w >> 1) << 5;
  const int wn = (w & 1) * (NF << 4);
  const int lr = lane & 15, lk = (lane >> 4) << 3;
  #pragma unroll
  for (int ks = 0; ks < 2; ++ks) {
    const int ko = ks * 32 + lk;
    short8 a0 = *(const short8*)&As[(wm + lr)*72 + ko];
    short8 a1 = *(const short8*)&As[(wm + 16 + lr)*72 + ko];
    #pragma unroll
    for (int f = 0; f < NF; ++f) {
      short8 b = *(const short8*)&Ws[(wn + f*16 + lr)*72 + ko];
      acc[0][f] = __builtin_amdgcn_mfma_f32_16x16x32_bf16(a0, b, acc[0][f], 0, 0, 0);
      acc[1][f] = __builtin_amdgcn_mfma_f32_16x16x32_bf16(a1, b, acc[1][f], 0, 0, 0);
    }
  }
}

// mma variant: A resident in q2l [64][264], full-K; W staged per-64 chunk (r6-verified)
template<int NF>
__device__ __forceinline__ void mma_q2l(const short* q2l, const short* Ws, int k0,
                                        f32x4 acc[2][NF]) {
  const int lane = threadIdx.x & 63;
  const int w = threadIdx.x >> 6;
  const int wm = (w >> 1) << 5;
  const int wn = (w & 1) * (NF << 4);
  const int lr = lane & 15, lk = (lane >> 4) << 3;
  #pragma unroll
  for (int ks = 0; ks < 2; ++ks) {
    const int kl = ks * 32 + lk;
    short8 a0 = *(const short8*)&q2l[(wm + lr)*264 + k0 + kl];
    short8 a1 = *(const short8*)&q2l[(wm + 16 + lr)*264 + k0 + kl];
    #pragma unroll
    for (int f = 0; f < NF; ++f) {
      short8 b = *(const short8*)&Ws[(wn + f*16 + lr)*72 + kl];
      acc[0][f] = __builtin_amdgcn_mfma_f32_16x16x32_bf16(a0, b, acc[0][f], 0, 0, 0);
      acc[1][f] = __builtin_amdgcn_mfma_f32_16x16x32_bf16(a1, b, acc[1][f], 0, 0, 0);
    }
  }
}

template<int NF>
__device__ void run_gemm(short* As, short* Ws, const Aseg& a, const short* W, int ldw,
                         int m0, int n0, int Nmax, f32x4 acc[2][NF], int kb, int ke) {
  for (int k0 = kb; k0 < ke; k0 += 64) {
    __syncthreads();
    stageA(As, a, m0, k0);
    stageW(Ws, W, ldw, n0, NF*32, Nmax, k0, a.K);
    __syncthreads();
    mma_tile<NF>(As, Ws, acc);
  }
}

// C/D layout (m89-verified): col = lane&15, row = (lane>>4)*4 + reg
template<int NF>
__device__ void epi_generic(f32x4 acc[2][NF], int m0, int n0, int Nmax, const float* bias,
                            int relu, float* outF, long rsF, unsigned short* outB, int rsB) {
  const int lane = threadIdx.x & 63;
  const int w = threadIdx.x >> 6;
  const int wm = (w >> 1) << 5, wn = (w & 1) * (NF << 4);
  #pragma unroll
  for (int mt = 0; mt < 2; ++mt)
  #pragma unroll
  for (int f = 0; f < NF; ++f)
  #pragma unroll
  for (int r = 0; r < 4; ++r) {
    const int m = m0 + wm + mt*16 + ((lane >> 4) << 2) + r;
    const int n = n0 + wn + f*16 + (lane & 15);
    if (n < Nmax) {
      float v = acc[mt][f][r];
      if (bias) v += bias[n];
      if (relu) v = fmaxf(v, 0.f);
      if (outF) outF[(long)m * rsF + n] = v;
      if (outB) outB[(long)m * rsB + n] = f2bf(v);
    }
  }
}

// q2 epilogue -> LDS band [64][264] (local rows), relu+bias (r6-verified)
template<int NF>
__device__ void epi_q2l(f32x4 acc[2][NF], int n0, const float* bias, short* q2l) {
  const int lane = threadIdx.x & 63;
  const int w = threadIdx.x >> 6;
  const int wm = (w >> 1) << 5, wn = (w & 1) * (NF << 4);
  #pragma unroll
  for (int mt = 0; mt < 2; ++mt)
  #pragma unroll
  for (int f = 0; f < NF; ++f)
  #pragma unroll
  for (int r = 0; r < 4; ++r) {
    const int ml = wm + mt*16 + ((lane >> 4) << 2) + r;
    const int n = n0 + wn + f*16 + (lane & 15);
    if (n < FD) {
      float v = fmaxf(acc[mt][f][r] + bias[n], 0.f);
      q2l[ml*264 + n] = (short)f2bf(v);
    }
  }
}

// heads epilogue; wy gates the y1/y5/y6 stores (postb always written)
template<int NF>
__device__ void epi_heads(f32x4 acc[2][NF], int m0, int n0, const float* biasI,
                          const float* noise, long rs, float* outMu, float* outStd,
                          float* outComb, unsigned short* postbf, int wy) {
  const int lane = threadIdx.x & 63;
  const int w = threadIdx.x >> 6;
  const int wm = (w >> 1) << 5, wn = (w & 1) * (NF << 4);
  #pragma unroll
  for (int mt = 0; mt < 2; ++mt)
  #pragma unroll
  for (int f = 0; f < NF; ++f)
  #pragma unroll
  for (int r = 0; r < 4; ++r) {
    const int m = m0 + wm + mt*16 + ((lane >> 4) << 2) + r;
    const int n = n0 + wn + f*16 + (lane & 15);
    float v = acc[mt][f][r] + biasI[n];
    if (n & 1) v = softp(v) + 0.1f;               // std lanes
    float partner = __shfl_xor(v, 1);
    const int l = n >> 1;
    if (n & 1) {
      if (wy) outStd[(long)m * rs + l] = v;
    } else {
      float comb = v + partner * noise[(long)m * rs + l];
      if (wy) {
        outMu[(long)m * rs + l] = v;
        outComb[(long)m * rs + l] = comb;
      }
      if (postbf) postbf[m * LD + l] = f2bf(comb);
    }
  }
}

// ---------------- pipelined gload_lds path (r2-verified) ----------------
__device__ __forceinline__ void gl_lds16(const void* g, void* l) {
  __builtin_amdgcn_global_load_lds(
      (const __attribute__((address_space(1))) unsigned int*)g,
      (__attribute__((address_space(3))) unsigned int*)l, 16, 0, 0);
}

#define PIPE_BAR() do { \
    asm volatile("s_waitcnt vmcnt(0)" ::: "memory"); \
    __builtin_amdgcn_s_barrier(); \
    __builtin_amdgcn_sched_barrier(0); \
  } while (0)

// stage a 64x64 bf16 tile: LDS linear [64][64]; global source chunk XOR-swizzled (rule #21)
__device__ __forceinline__ void stage_pipe_rows(short* dst, const short* g, long ldw,
                                                int rbase, int k0) {
  const int w = threadIdx.x >> 6, l = threadIdx.x & 63;
  #pragma unroll
  for (int i = 0; i < 2; ++i) {
    const int inst = w*2 + i;
    const int row = inst*8 + (l >> 3);
    const int sc = (l & 7) ^ (row & 7);
    gl_lds16(g + (long)(rbase + row) * ldw + k0 + sc*8, dst + inst*512);
  }
}
// gi-slice W rows: 3 gates x 16 j-rows (rows 48-63 duplicate gate0; unused by MFMA)
__device__ __forceinline__ void stage_pipe_gi(short* dst, const short* W, int j0, int k0) {
  const int w = threadIdx.x >> 6, l = threadIdx.x & 63;
  #pragma unroll
  for (int i = 0; i < 2; ++i) {
    const int inst = w*2 + i;
    const int row = inst*8 + (l >> 3);
    const int g = (row >> 4) % 3;
    const int sc = (l & 7) ^ (row & 7);
    gl_lds16(W + (long)(g*2048 + j0 + (row & 15)) * 2048 + k0 + sc*8, dst + inst*512);
  }
}

template<int NF>
__device__ __forceinline__ void mma_swz(const short* As, const short* Ws, f32x4 acc[2][NF]) {
  const int lane = threadIdx.x & 63, w = threadIdx.x >> 6;
  const int wm = (w >> 1) << 5, wn = (w & 1) * (NF << 4);
  const int lr = lane & 15, lk = (lane >> 4) << 3;
  #pragma unroll
  for (int ks = 0; ks < 2; ++ks) {
    const int ko = ks*32 + lk; const int ca = ko >> 3;
    const int ra0 = wm + lr, ra1 = wm + 16 + lr;
    short8 a0 = *(const short8*)&As[ra0*64 + ((ca ^ (ra0 & 7)) << 3)];
    short8 a1 = *(const short8*)&As[ra1*64 + ((ca ^ (ra1 & 7)) << 3)];
    #pragma unroll
    for (int f = 0; f < NF; ++f) {
      const int rb = wn + f*16 + lr;
      short8 b = *(const short8*)&Ws[rb*64 + ((ca ^ (rb & 7)) << 3)];
      acc[0][f] = __builtin_amdgcn_mfma_f32_16x16x32_bf16(a0, b, acc[0][f], 0, 0, 0);
      acc[1][f] = __builtin_amdgcn_mfma_f32_16x16x32_bf16(a1, b, acc[1][f], 0, 0, 0);
    }
  }
}

__device__ __forceinline__ void mma_gi(const short* As, const short* Ws, f32x4 acc[3]) {
  const int lane = threadIdx.x & 63, w = threadIdx.x >> 6;
  const int lr = lane & 15, lk = (lane >> 4) << 3;
  #pragma unroll
  for (int ks = 0; ks < 2; ++ks) {
    const int ko = ks*32 + lk; const int ca = ko >> 3;
    const int ra = w*16 + lr;
    short8 av = *(const short8*)&As[ra*64 + ((ca ^ (ra & 7)) << 3)];
    #pragma unroll
    for (int f = 0; f < 3; ++f) {
      const int rb = f*16 + lr;
      short8 bv = *(const short8*)&Ws[rb*64 + ((ca ^ (rb & 7)) << 3)];
      acc[f] = __builtin_amdgcn_mfma_f32_16x16x32_bf16(av, bv, acc[f], 0, 0, 0);
    }
  }
}

// ---------------- args ----------------
struct CArgs {
  char* ws;
  const float* enc; const float* act; const float* nq;
  const float* b_e; const float* b_ih; const float* b_hh;
  const float* b_q1; const float* b_q2;
  float* y1; float* y2; float* y5; float* y6;
};

// ---------------- per-step device tiles (r2-verified) ----------------
__device__ void emb_tile(SMem& sm, const CArgs& A, int id, int t) {
  const int mi = id & 3, ni = id >> 2;          // 4 x 16 tiles (64x128)
  const int m0 = mi << 6, n0 = ni << 7;
  Aseg a{A.ws + O_POSTB, LD, LD, 0, (const char*)(A.act + (size_t)t*AD), TS*AD, 1, KE};
  f32x4 acc[2][4];
  for (int i=0;i<2;++i) for (int j=0;j<4;++j) acc[i][j] = z4();
  run_gemm<4>(sm.As, sm.Ws, a, (const short*)(A.ws + O_WE), KE, m0, n0, HD, acc, 0, 320);
  epi_generic<4>(acc, m0, n0, HD, A.b_e, 1, nullptr, 0, (unsigned short*)(A.ws + O_EMB), HD);
}

__device__ void gh_tile_pipe(SMemP& sm, const CArgs& A, int id) {
  const int xcd = id & 7, local = id >> 3;      // 48 locals per XCD
  const int mi = local & 3, nio = local >> 2;   // 4m x 12n
  const int m0 = mi << 6, n0 = xcd*768 + nio*64;
  const short* hB  = (const short*)(A.ws + O_HBF);
  const short* Whh = (const short*)(A.ws + O_WHH);
  f32x4 acc[2][2];
  for (int i=0;i<2;++i) for (int j=0;j<2;++j) acc[i][j] = z4();
  int cur = 0;
  stage_pipe_rows(sm.A[0], hB, HD, m0, 0);
  stage_pipe_rows(sm.W[0], Whh, HD, n0, 0);
  PIPE_BAR();
  for (int k0 = 0; k0 < HD; k0 += 64) {
    if (k0 + 64 < HD) {
      stage_pipe_rows(sm.A[cur^1], hB, HD, m0, k0 + 64);
      stage_pipe_rows(sm.W[cur^1], Whh, HD, n0, k0 + 64);
    }
    mma_swz<2>(sm.A[cur], sm.W[cur], acc);
    PIPE_BAR();
    cur ^= 1;
  }
  epi_generic<2>(acc, m0, n0, H3, A.b_hh, 0, (float*)(A.ws + O_GH), H3, nullptr, 0);
}

__device__ void gi_tile_pipe(SMemP& sm, const CArgs& A, int id, int t) {
  const int xcd = id & 7, local = id >> 3;      // 64 locals per XCD
  const int mi = local & 3, jl = local >> 2;    // 4m x 16j (16-wide)
  const int m0 = mi << 6, j0 = xcd*256 + jl*16;
  const short* eB  = (const short*)(A.ws + O_EMB);
  const short* Wih = (const short*)(A.ws + O_WIH);
  f32x4 acc[3]; acc[0] = z4(); acc[1] = z4(); acc[2] = z4();
  int cur = 0;
  stage_pipe_rows(sm.A[0], eB, HD, m0, 0);
  stage_pipe_gi(sm.W[0], Wih, j0, 0);
  PIPE_BAR();
  for (int k0 = 0; k0 < HD; k0 += 64) {
    if (k0 + 64 < HD) {
      stage_pipe_rows(sm.A[cur^1], eB, HD, m0, k0 + 64);
      stage_pipe_gi(sm.W[cur^1], Wih, j0, k0 + 64);
    }
    mma_gi(sm.A[cur], sm.W[cur], acc);
    PIPE_BAR();
    cur ^= 1;
  }
  // fused GRU gates: lane holds (i_r,i_z,i_n) for its (m, j)
  const int lane = threadIdx.x & 63, w = threadIdx.x >> 6;
  const int lr = lane & 15;
  const int j = j0 + lr;
  float* hF = (float*)(A.ws + O_HF);
  unsigned short* hB = (unsigned short*)(A.ws + O_HBF);
  const float* gh = (const float*)(A.ws + O_GH);
  #pragma unroll
  for (int r = 0; r < 4; ++r) {
    const int m = m0 + w*16 + ((lane >> 4) << 2) + r;
    const float* g = gh + (size_t)m * H3;
    const float ir = acc[0][r] + A.b_ih[j]        + g[j];
    const float iz = acc[1][r] + A.b_ih[HD + j]   + g[HD + j];
    const float in_ = acc[2][r] + A.b_ih[2*HD + j];
    const float rr = sigm(ir), zz = sigm(iz);
    const float nn = tanh_f(in_ + rr * g[2*HD + j]);
    const float hv = (1.f - zz) * nn + zz * hF[(size_t)m*HD + j];
    hF[(size_t)m*HD + j] = hv;
    hB[(size_t)m*HD + j] = f2bf(hv);
    A.y2[(size_t)m * (TS*HD) + (size_t)t*HD + j] = hv;
  }
}

// q1 split-K 4 (r3-verified): 32 wgs = 4 slices x (4m x 2n)
__device__ void q1_tile4(SMem& sm, const CArgs& A, int id, int t) {
  const int s = id >> 3, rest = id & 7;
  const int mi = rest & 3, ni = rest >> 2;
  const int m0 = mi << 6, n0 = ni << 7;
  Aseg a{A.ws + O_HBF, HD, HD, 0, (const char*)(A.enc + (size_t)t*ED), TS*ED, 1, KQ};
  f32x4 acc[2][4];
  for (int i=0;i<2;++i) for (int j=0;j<4;++j) acc[i][j] = z4();
  run_gemm<4>(sm.As, sm.Ws, a, (const short*)(A.ws + O_WQ1), KQ, m0, n0, FD, acc,
              s*768, s*768+768);
  epi_generic<4>(acc, m0, n0, FD, nullptr, 0,
                 (float*)(A.ws + O_Q1P) + (size_t)s*NB*256, 256, nullptr, 0);
}

// ---------------- per-step kernels (stream-ordered, 3/step) ----------------
__global__ __launch_bounds__(256, 2) void k_step1(CArgs A, int t) {   // prologue only
  __shared__ SMemU sm;
  if (blockIdx.x < 384) gh_tile_pipe(sm.p, A, blockIdx.x);
  else                  emb_tile(sm.legacy, A, blockIdx.x - 384, t);
}
__global__ __launch_bounds__(256, 2) void k_gi(CArgs A, int t) {      // gi + gates -> h(t)
  __shared__ SMemP sm;
  gi_tile_pipe(sm, A, blockIdx.x, t);
}
// k_mid: q1(t) [32 wgs] || gh(t+1) [384 wgs]
__global__ __launch_bounds__(256, 2) void k_mid(CArgs A, int t) {
  __shared__ SMemU sm;
  if (blockIdx.x < 32) { q1_tile4(sm.legacy, A, blockIdx.x, t); return; }
  if (t + 1 >= TS) return;
  gh_tile_pipe(sm.p, A, blockIdx.x - 32);
}

// k_tail: 32 wgs = 4 bands x 8 emb-chunks. Each wg: q2 band (4-slice reduce, A staged
// once per k0) -> LDS; full heads band -> postb (+y if chunk 0); emb(t+1) chunk.
__global__ __launch_bounds__(256, 2) void k_tail(CArgs A, int t) {
  __shared__ SMemQH sm;
  const int id = blockIdx.x;
  const int mi = id & 3, ci = id >> 2;
  const int m0 = mi << 6;

  // phase 1: q2 band = relu(q1_red @ Wq2^T + bq2) -> q2l [64][264]
  const short* Wq2 = (const short*)(A.ws + O_WQ2);
  {
    f32x4 acc0[2][4], acc1[2][4];
    for (int i=0;i<2;++i) for (int j=0;j<4;++j) { acc0[i][j] = z4(); acc1[i][j] = z4(); }
    for (int k0 = 0; k0 < 256; k0 += 64) {
      __syncthreads();
      stageA_red4(sm.As, (const float*)(A.ws + O_Q1P), A.b_q1, m0, k0);
      stageW(sm.Ws, Wq2, FD, 0, 128, FD, k0, FD);
      __syncthreads();
      mma_tile<4>(sm.As, sm.Ws, acc0);
      __syncthreads();
      stageW(sm.Ws, Wq2, FD, 128, 128, FD, k0, FD);
      __syncthreads();
      mma_tile<4>(sm.As, sm.Ws, acc1);
    }
    epi_q2l<4>(acc0, 0, A.b_q2, sm.q2l);
    epi_q2l<4>(acc1, 128, A.b_q2, sm.q2l);
  }
  // zero pad cols 200..263
  for (int i = threadIdx.x; i < 64*64; i += 256)
    sm.q2l[(i >> 6)*264 + 200 + (i & 63)] = 0;
  __syncthreads();

  // phase 2: full heads band (4 quarters), K=256 (A zeros >=200, W masked at 200)
  const short* Wqms = (const short*)(A.ws + O_WQMS);
  unsigned short* postb = (unsigned short*)(A.ws + O_POSTB);
  #pragma unroll 1
  for (int qn = 0; qn < 4; ++qn) {
    f32x4 acc[2][4];
    for (int i=0;i<2;++i) for (int j=0;j<4;++j) acc[i][j] = z4();
    for (int k0 = 0; k0 < 256; k0 += 64) {
      __syncthreads();
      stageW(sm.Ws, Wqms, FD, qn*128, 128, 512, k0, FD);
      __syncthreads();
      mma_q2l<4>(sm.q2l, sm.Ws, k0, acc);
    }
    epi_heads<4>(acc, m0, qn*128, (const float*)(A.ws + O_BQMS),
                 A.nq + (size_t)t*LD, (long)TS*LD,
                 A.y5 + (size_t)t*LD, A.y6 + (size_t)t*LD, A.y1 + (size_t)t*LD,
                 postb, ci == 0);
  }

  // phase 3: emb(t+1) chunk [m-band x 256 cols] from [postb|act(t+1)]
  if (t + 1 >= TS) return;
  asm volatile("s_waitcnt vmcnt(0)" ::: "memory");   // own postb stores done
  __syncthreads();
  Aseg a{A.ws + O_POSTB, LD, LD, 0, (const char*)(A.act + (size_t)(t+1)*AD), TS*AD, 1, KE};
  unsigned short* embB = (unsigned short*)(A.ws + O_EMB);
  #pragma unroll 1
  for (int cc = 0; cc < 2; ++cc) {
    const int n0 = ci*256 + cc*128;
    f32x4 acc[2][4];
    for (int i=0;i<2;++i) for (int j=0;j<4;++j) acc[i][j] = z4();
    run_gemm<4>(sm.As, sm.Ws, a, (const short*)(A.ws + O_WE), KE, m0, n0, HD, acc, 0, 320);
    epi_generic<4>(acc, m0, n0, HD, A.b_e, 1, nullptr, 0, embB, HD);
  }
}

// ---------------- init: f32 -> bf16 weights, interleaves, state ----------------
__global__ void k_init(char* ws, const float* prevs, const float* prevh,
  const float* We, const float* Wih, const float* Whh,
  const float* Wp1, const float* Wp2, const float* Wpm, const float* Wps,
  const float* Wq1, const float* Wq2, const float* Wqm, const float* Wqs,
  const float* Wr1, const float* Wr2, const float* Wr3,
  const float* bpm, const float* bps, const float* bqm, const float* bqs) {
  const size_t stride = (size_t)gridDim.x * blockDim.x;
  for (size_t i = (size_t)blockIdx.x*blockDim.x + threadIdx.x; i < 12582912ull; i += stride) {
    ((unsigned short*)(ws + O_WIH))[i] = f2bf(Wih[i]);
    ((unsigned short*)(ws + O_WHH))[i] = f2bf(Whh[i]);
    if (i < 589824)  ((unsigned short*)(ws + O_WE))[i]  = f2bf(We[i]);
    if (i < 614400)  ((unsigned short*)(ws + O_WQ1))[i] = f2bf(Wq1[i]);
    if (i < 409600)  ((unsigned short*)(ws + O_WP1))[i] = f2bf(Wp1[i]);
    if (i < 460800)  ((unsigned short*)(ws + O_WR1))[i] = f2bf(Wr1[i]);
    if (i < 40000) {
      ((unsigned short*)(ws + O_WQ2))[i] = f2bf(Wq2[i]);
      ((unsigned short*)(ws + O_WP2))[i] = f2bf(Wp2[i]);
      ((unsigned short*)(ws + O_WR2))[i] = f2bf(Wr2[i]);
    }
    if (i < 200) ((unsigned short*)(ws + O_WR3))[i] = f2bf(Wr3[i]);
    if (i < 102400) {
      const int r = (int)(i / 200), c = (int)(i % 200);
      ((unsigned short*)(ws + O_WQMS))[i] = f2bf(((r & 1) ? Wqs : Wqm)[(r >> 1)*200 + c]);
      ((unsigned short*)(ws + O_WPMS))[i] = f2bf(((r & 1) ? Wps : Wpm)[(r >> 1)*200 + c]);
    }
    if (i < 512) {
      ((float*)(ws + O_BQMS))[i] = ((i & 1) ? bqs : bqm)[i >> 1];
      ((float*)(ws + O_BPMS))[i] = ((i & 1) ? bps : bpm)[i >> 1];
    }
    if (i < 65536) ((unsigned short*)(ws + O_POSTB))[i] = f2bf(prevs[i]);
    if (i < 524288) {
      ((unsigned short*)(ws + O_HBF))[i] = f2bf(prevh[i]);
      ((float*)(ws + O_HF))[i] = prevh[i];
    }
  }
}

// ---------------- post-loop batched prior/reward chains (M = 32768) ----------------
__global__ __launch_bounds__(256, 2) void k_big(int mode, char* ws,
  const float* y1, const float* y2, float* y0, float* y3, float* y4,
  const float* npn, const float* bp1, const float* bp2, const float* br1, const float* br2) {
  __shared__ SMem sm;
  if (mode == 2) { // prior heads + prior_s
    for (int tile = blockIdx.x; tile < 2048; tile += gridDim.x) {
      const int mi = tile >> 2, ni = tile & 3;
      const int m0 = mi << 6, n0 = ni << 7;
      Aseg a{ws + O_P2B, FD, FD, 0, nullptr, 0, 0, FD};
      f32x4 acc[2][4];
      for (int i=0;i<2;++i) for (int j=0;j<4;++j) acc[i][j] = z4();
      run_gemm<4>(sm.As, sm.Ws, a, (const short*)(ws + O_WPMS), FD, m0, n0, 512, acc, 0, 256);
      epi_heads<4>(acc, m0, n0, (const float*)(ws + O_BPMS), npn, 256, y3, y4, y0,
                   nullptr, 1);
    }
    return;
  }
  for (int tile = blockIdx.x; tile < 1024; tile += gridDim.x) {
    const int mi = tile >> 1, ni = tile & 1;
    const int m0 = mi << 6, n0 = ni << 7;
    Aseg a; const short* W; const float* bias;
    if (mode == 0)      { a = {(const char*)y2, HD, HD, 1, nullptr, 0, 0, HD}; W = (const short*)(ws + O_WP1); bias = bp1; }
    else if (mode == 1) { a = {ws + O_P1B, FD, FD, 0, nullptr, 0, 0, FD};      W = (const short*)(ws + O_WP2); bias = bp2; }
    else if (mode == 3) { a = {(const char*)y1, LD, LD, 1, (const char*)y2, HD, 1, KR}; W = (const short*)(ws + O_WR1); bias = br1; }
    else                { a = {ws + O_P1B, FD, FD, 0, nullptr, 0, 0, FD};      W = (const short*)(ws + O_WR2); bias = br2; }
    f32x4 acc[2][4];
    for (int i=0;i<2;++i) for (int j=0;j<4;++j) acc[i][j] = z4();
    const int ke = (a.K + 63) & ~63;
    run_gemm<4>(sm.As, sm.Ws, a, W, a.K, m0, n0, FD, acc, 0, ke);
    unsigned short* outp = (unsigned short*)(ws + ((mode == 0 || mode == 3) ? O_P1B : O_P2B));
    epi_generic<4>(acc, m0, n0, FD, bias, 1, nullptr, 0, outp, FD);
  }
}

__global__ void k_r3(char* ws, const float* br3, float* y7) {
  __shared__ float w3[200];
  for (int i = threadIdx.x; i < 200; i += 256) w3[i] = bf2f(((unsigned short*)(ws + O_WR3))[i]);
  __syncthreads();
  const int m = blockIdx.x * 256 + threadIdx.x;
  const unsigned short* r2 = (const unsigned short*)(ws + O_P2B) + (size_t)m * FD;
  float s = br3[0];
  for (int k = 0; k < FD; k += 8) {
    short8 v = *(const short8*)(r2 + k);
    #pragma unroll
    for (int j = 0; j < 8; ++j) s += bf2f((unsigned short)v[j]) * w3[k + j];
  }
  y7[m] = s;
}

// ---------------- host launcher ----------------
extern "C" void kernel_launch(void* const* d_in, const int* in_sizes, int n_in,
                              void* d_out, int out_size, void* d_ws, size_t ws_size,
                              hipStream_t stream) {
  (void)in_sizes; (void)n_in; (void)out_size; (void)ws_size;
  char* ws = (char*)d_ws;
  #define FIN(i) ((const float*)d_in[i])
  float* out = (float*)d_out;
  float* y0 = out + Y0; float* y1 = out + Y1; float* y2 = out + Y2; float* y3 = out + Y3;
  float* y4 = out + Y4; float* y5 = out + Y5; float* y6 = out + Y6; float* y7 = out + Y7;

  k_init<<<2048, 256, 0, stream>>>(ws, FIN(0), FIN(1), FIN(6), FIN(8), FIN(10),
    FIN(12), FIN(14), FIN(16), FIN(18), FIN(20), FIN(22), FIN(24), FIN(26),
    FIN(28), FIN(30), FIN(32), FIN(17), FIN(19), FIN(25), FIN(27));

  CArgs ca;
  ca.ws = ws; ca.enc = FIN(2); ca.act = FIN(3); ca.nq = FIN(5);
  ca.b_e = FIN(7); ca.b_ih = FIN(9); ca.b_hh = FIN(11); ca.b_q1 = FIN(21); ca.b_q2 = FIN(23);
  ca.y1 = y1; ca.y2 = y2; ca.y5 = y5; ca.y6 = y6;

  k_step1<<<448, 256, 0, stream>>>(ca, 0);     // prologue: gh(0) + emb(0)
  for (int t = 0; t < TS; ++t) {
    k_gi  <<<512, 256, 0, stream>>>(ca, t);    // gi + fused gates -> h(t), y2
    k_mid <<<416, 256, 0, stream>>>(ca, t);    // q1(t) || gh(t+1)
    k_tail<<<32,  256, 0, stream>>>(ca, t);    // q2 -> heads/post -> emb(t+1)
  }

  k_big<<<2048, 256, 0, stream>>>(0, ws, y1, y2, y0, y3, y4, FIN(4), FIN(13), FIN(15), FIN(29), FIN(31));
  k_big<<<2048, 256, 0, stream>>>(1, ws, y1, y2, y0, y3, y4, FIN(4), FIN(13), FIN(15), FIN(29), FIN(31));
  k_big<<<2048, 256, 0, stream>>>(2, ws, y1, y2, y0, y3, y4, FIN(4), FIN(13), FIN(15), FIN(29), FIN(31));
  k_big<<<2048, 256, 0, stream>>>(3, ws, y1, y2, y0, y3, y4, FIN(4), FIN(13), FIN(15), FIN(29), FIN(31));
  k_big<<<2048, 256, 0, stream>>>(4, ws, y1, y2, y0, y3, y4, FIN(4), FIN(13), FIN(15), FIN(29), FIN(31));
  k_r3<<<128, 256, 0, stream>>>(ws, FIN(33), y7);
}

// Round 8
// 15461.823 us; speedup vs baseline: 1.6583x; 1.6583x over previous
//
#include <hip/hip_runtime.h>
#include <hip/hip_bf16.h>

// ---------------- problem constants ----------------
#define TS 128
#define NB 256
#define HD 2048
#define H3 6144
#define LD 256
#define ED 1024
#define AD 32
#define FD 200
#define KE 288     // L + A
#define KQ 3072    // H + E
#define KR 2304    // L + H
#define MT 32768   // NB * TS

typedef __attribute__((ext_vector_type(8))) short short8;
typedef __attribute__((ext_vector_type(4))) float f32x4;

// ---------------- workspace layout (r2-identical) ----------------
constexpr size_t alup(size_t x) { return (x + 255) & ~size_t(255); }
constexpr size_t O_WE   = 0;
constexpr size_t O_WIH  = alup(O_WE   + 2ull*2048*288);
constexpr size_t O_WHH  = alup(O_WIH  + 2ull*6144*2048);
constexpr size_t O_WQ1  = alup(O_WHH  + 2ull*6144*2048);
constexpr size_t O_WQ2  = alup(O_WQ1  + 2ull*200*3072);
constexpr size_t O_WQMS = alup(O_WQ2  + 2ull*200*200);   // interleaved [qm0,qs0,...] rows
constexpr size_t O_WP1  = alup(O_WQMS + 2ull*512*200);
constexpr size_t O_WP2  = alup(O_WP1  + 2ull*200*2048);
constexpr size_t O_WPMS = alup(O_WP2  + 2ull*200*200);
constexpr size_t O_WR1  = alup(O_WPMS + 2ull*512*200);
constexpr size_t O_WR2  = alup(O_WR1  + 2ull*200*2304);
constexpr size_t O_WR3  = alup(O_WR2  + 2ull*200*200);
constexpr size_t O_BQMS = alup(O_WR3  + 2ull*200);       // f32[512] interleaved bias
constexpr size_t O_BPMS = alup(O_BQMS + 4ull*512);
constexpr size_t O_POSTB= alup(O_BPMS + 4ull*512);       // bf16 [256][256]
constexpr size_t O_HBF  = alup(O_POSTB+ 2ull*NB*LD);     // bf16 [256][2048]
constexpr size_t O_HF   = alup(O_HBF  + 2ull*NB*HD);     // f32  [256][2048]
constexpr size_t O_EMB  = alup(O_HF   + 4ull*NB*HD);     // bf16 [256][2048]
constexpr size_t O_GH   = alup(O_EMB  + 2ull*NB*HD);     // f32  [256][6144]
constexpr size_t O_Q1P  = alup(O_GH   + 4ull*NB*H3);     // f32  [16][256][256] split-K partials
constexpr size_t O_Q2   = alup(O_Q1P  + 4ull*16*NB*256); // bf16 [256][200]
constexpr size_t O_BARF = alup(O_Q2   + 2ull*NB*FD);
constexpr size_t O_BARC = alup(O_BARF + 4ull*(64*32+64));
constexpr size_t O_P1B  = alup(O_BARC + 4ull*(16*32+64));// bf16 [32768][200]
constexpr size_t O_P2B  = alup(O_P1B  + 2ull*(size_t)MT*FD);
constexpr size_t O_END  = alup(O_P2B  + 2ull*(size_t)MT*FD); // ~96.6 MB

// output offsets (f32 elements)
#define Y0 0ull
#define Y1 8388608ull
#define Y2 16777216ull
#define Y3 83886080ull
#define Y4 92274688ull
#define Y5 100663296ull
#define Y6 109051904ull
#define Y7 117440512ull

// ---------------- small helpers ----------------
__device__ __forceinline__ unsigned short f2bf(float f) {
  union { float f; unsigned u; } v; v.f = f;
  unsigned r = v.u + 0x7fffu + ((v.u >> 16) & 1u);
  return (unsigned short)(r >> 16);
}
__device__ __forceinline__ float bf2f(unsigned short u) {
  union { unsigned u; float f; } v; v.u = ((unsigned)u) << 16;
  return v.f;
}
__device__ __forceinline__ float sigm(float x) { return 1.f / (1.f + __expf(-x)); }
__device__ __forceinline__ float tanh_f(float x) {
  float e = __expf(-2.f * fabsf(x));
  float t = (1.f - e) / (1.f + e);
  return x >= 0.f ? t : -t;
}
__device__ __forceinline__ float softp(float x) { return x > 15.f ? x : log1pf(__expf(x)); }
__device__ __forceinline__ f32x4 z4() { f32x4 z; z[0]=0.f; z[1]=0.f; z[2]=0.f; z[3]=0.f; return z; }

struct SMem {
  alignas(16) short As[64*72];   // legacy reg-staged path
  alignas(16) short Ws[128*72];
};
struct SMemP {                   // pipelined gload_lds path: linear, TRIPLE-buffered (T4)
  alignas(16) short A[3][64*64];
  alignas(16) short W[3][64*64];
};
union SMemU { SMemP p; SMem legacy; };

struct Aseg {  // A operand: up to 2 concatenated segments, each f32 or bf16
  const char* p0; int lda0; int K0; int f0;
  const char* p1; int lda1; int f1;
  int K;
};

// ---------------- legacy reg-staged path (round-1/2, verified) ----------------
__device__ __forceinline__ void stageA(short* As, const Aseg& a, int m0, int k0) {
  const int t = threadIdx.x;
  const int row = t >> 2;
  const int cb = (t & 3) << 4;
  #pragma unroll
  for (int i = 0; i < 2; ++i) {
    const int c = cb + i * 8;
    const int gk = k0 + c;
    short8 v = {};
    if (gk < a.K) {
      const char* p; long idx; int isf;
      if (gk < a.K0) { p = a.p0; idx = (long)(m0 + row) * a.lda0 + gk; isf = a.f0; }
      else           { p = a.p1; idx = (long)(m0 + row) * a.lda1 + (gk - a.K0); isf = a.f1; }
      if (isf) {
        const float* pf = (const float*)p + idx;
        #pragma unroll
        for (int j = 0; j < 8; ++j) v[j] = (short)f2bf(pf[j]);
      } else {
        v = *(const short8*)((const short*)p + idx);
      }
    }
    *(short8*)&As[row*72 + c] = v;
  }
}

__device__ __forceinline__ void stageW(short* Ws, const short* W, int ldw, int n0, int BN,
                                       int Nmax, int k0, int K) {
  const int nch = BN << 3;
  for (int id = threadIdx.x; id < nch; id += 256) {
    const int row = id >> 3;
    const int c = (id & 7) << 3;
    const int gk = k0 + c;
    int gr = n0 + row; gr = gr < Nmax ? gr : Nmax - 1;
    short8 v = {};
    if (gk < K) v = *(const short8*)(W + (long)gr * ldw + gk);
    *(short8*)&Ws[row*72 + c] = v;
  }
}

// q2 A-stage: A = relu(sum_s q1_partial[s] + bq1), K=200, 16 slices (r2-verified)
__device__ __forceinline__ void stageA_red(short* As, const float* q1p, const float* bq1,
                                           int m0, int k0) {
  const int t = threadIdx.x;
  const int row = t >> 2;
  const int cb = (t & 3) << 4;
  #pragma unroll
  for (int i = 0; i < 2; ++i) {
    const int c = cb + i * 8;
    const int gk = k0 + c;
    short8 v = {};
    if (gk < FD) {
      float s[8];
      #pragma unroll
      for (int j = 0; j < 8; ++j) s[j] = bq1[gk + j];
      for (int ss = 0; ss < 16; ++ss) {
        const float* p = q1p + (size_t)ss * NB * 256 + (size_t)(m0 + row) * 256 + gk;
        #pragma unroll
        for (int j = 0; j < 8; ++j) s[j] += p[j];
      }
      #pragma unroll
      for (int j = 0; j < 8; ++j) v[j] = (short)f2bf(fmaxf(s[j], 0.f));
    }
    *(short8*)&As[row*72 + c] = v;
  }
}

template<int NF>
__device__ __forceinline__ void mma_tile(const short* As, const short* Ws, f32x4 acc[2][NF]) {
  const int lane = threadIdx.x & 63;
  const int w = threadIdx.x >> 6;
  const int wm = (w >> 1) << 5;
  const int wn = (w & 1) * (NF << 4);
  const int lr = lane & 15, lk = (lane >> 4) << 3;
  #pragma unroll
  for (int ks = 0; ks < 2; ++ks) {
    const int ko = ks * 32 + lk;
    short8 a0 = *(const short8*)&As[(wm + lr)*72 + ko];
    short8 a1 = *(const short8*)&As[(wm + 16 + lr)*72 + ko];
    #pragma unroll
    for (int f = 0; f < NF; ++f) {
      short8 b = *(const short8*)&Ws[(wn + f*16 + lr)*72 + ko];
      acc[0][f] = __builtin_amdgcn_mfma_f32_16x16x32_bf16(a0, b, acc[0][f], 0, 0, 0);
      acc[1][f] = __builtin_amdgcn_mfma_f32_16x16x32_bf16(a1, b, acc[1][f], 0, 0, 0);
    }
  }
}

template<int NF>
__device__ void run_gemm(SMem& sm, const Aseg& a, const short* W, int ldw, int m0, int n0,
                         int Nmax, f32x4 acc[2][NF], int kb, int ke) {
  for (int k0 = kb; k0 < ke; k0 += 64) {
    __syncthreads();
    stageA(sm.As, a, m0, k0);
    stageW(sm.Ws, W, ldw, n0, NF*32, Nmax, k0, a.K);
    __syncthreads();
    mma_tile<NF>(sm.As, sm.Ws, acc);
  }
}

// C/D layout (m89-verified): col = lane&15, row = (lane>>4)*4 + reg
template<int NF>
__device__ void epi_generic(f32x4 acc[2][NF], int m0, int n0, int Nmax, const float* bias,
                            int relu, float* outF, long rsF, unsigned short* outB, int rsB) {
  const int lane = threadIdx.x & 63;
  const int w = threadIdx.x >> 6;
  const int wm = (w >> 1) << 5, wn = (w & 1) * (NF << 4);
  #pragma unroll
  for (int mt = 0; mt < 2; ++mt)
  #pragma unroll
  for (int f = 0; f < NF; ++f)
  #pragma unroll
  for (int r = 0; r < 4; ++r) {
    const int m = m0 + wm + mt*16 + ((lane >> 4) << 2) + r;
    const int n = n0 + wn + f*16 + (lane & 15);
    if (n < Nmax) {
      float v = acc[mt][f][r];
      if (bias) v += bias[n];
      if (relu) v = fmaxf(v, 0.f);
      if (outF) outF[(long)m * rsF + n] = v;
      if (outB) outB[(long)m * rsB + n] = f2bf(v);
    }
  }
}

template<int NF>
__device__ void epi_heads(f32x4 acc[2][NF], int m0, int n0, const float* biasI,
                          const float* noise, long rs, float* outMu, float* outStd,
                          float* outComb, unsigned short* postbf) {
  const int lane = threadIdx.x & 63;
  const int w = threadIdx.x >> 6;
  const int wm = (w >> 1) << 5, wn = (w & 1) * (NF << 4);
  #pragma unroll
  for (int mt = 0; mt < 2; ++mt)
  #pragma unroll
  for (int f = 0; f < NF; ++f)
  #pragma unroll
  for (int r = 0; r < 4; ++r) {
    const int m = m0 + wm + mt*16 + ((lane >> 4) << 2) + r;
    const int n = n0 + wn + f*16 + (lane & 15);
    float v = acc[mt][f][r] + biasI[n];
    if (n & 1) v = softp(v) + 0.1f;               // std lanes
    float partner = __shfl_xor(v, 1);
    const int l = n >> 1;
    if (n & 1) {
      outStd[(long)m * rs + l] = v;
    } else {
      outMu[(long)m * rs + l] = v;
      float comb = v + partner * noise[(long)m * rs + l];
      outComb[(long)m * rs + l] = comb;
      if (postbf) postbf[m * LD + l] = f2bf(comb);
    }
  }
}

// ---------------- pipelined gload_lds path ----------------
__device__ __forceinline__ void gl_lds16(const void* g, void* l) {
  __builtin_amdgcn_global_load_lds(
      (const __attribute__((address_space(1))) unsigned int*)g,
      (__attribute__((address_space(3))) unsigned int*)l, 16, 0, 0);
}

// stage a 64x64 bf16 tile: LDS linear [64][64]; global source chunk XOR-swizzled (rule #21)
__device__ __forceinline__ void stage_pipe_rows(short* dst, const short* g, long ldw,
                                                int rbase, int k0) {
  const int w = threadIdx.x >> 6, l = threadIdx.x & 63;
  #pragma unroll
  for (int i = 0; i < 2; ++i) {
    const int inst = w*2 + i;
    const int row = inst*8 + (l >> 3);
    const int sc = (l & 7) ^ (row & 7);
    gl_lds16(g + (long)(rbase + row) * ldw + k0 + sc*8, dst + inst*512);
  }
}
// gi-slice W rows: 3 gates x 16 j-rows (rows 48-63 duplicate gate0; unused by MFMA)
__device__ __forceinline__ void stage_pipe_gi(short* dst, const short* W, int j0, int k0) {
  const int w = threadIdx.x >> 6, l = threadIdx.x & 63;
  #pragma unroll
  for (int i = 0; i < 2; ++i) {
    const int inst = w*2 + i;
    const int row = inst*8 + (l >> 3);
    const int g = (row >> 4) % 3;
    const int sc = (l & 7) ^ (row & 7);
    gl_lds16(W + (long)(g*2048 + j0 + (row & 15)) * 2048 + k0 + sc*8, dst + inst*512);
  }
}

template<int NF>
__device__ __forceinline__ void mma_swz(const short* As, const short* Ws, f32x4 acc[2][NF]) {
  const int lane = threadIdx.x & 63, w = threadIdx.x >> 6;
  const int wm = (w >> 1) << 5, wn = (w & 1) * (NF << 4);
  const int lr = lane & 15, lk = (lane >> 4) << 3;
  #pragma unroll
  for (int ks = 0; ks < 2; ++ks) {
    const int ko = ks*32 + lk; const int ca = ko >> 3;
    const int ra0 = wm + lr, ra1 = wm + 16 + lr;
    short8 a0 = *(const short8*)&As[ra0*64 + ((ca ^ (ra0 & 7)) << 3)];
    short8 a1 = *(const short8*)&As[ra1*64 + ((ca ^ (ra1 & 7)) << 3)];
    #pragma unroll
    for (int f = 0; f < NF; ++f) {
      const int rb = wn + f*16 + lr;
      short8 b = *(const short8*)&Ws[rb*64 + ((ca ^ (rb & 7)) << 3)];
      acc[0][f] = __builtin_amdgcn_mfma_f32_16x16x32_bf16(a0, b, acc[0][f], 0, 0, 0);
      acc[1][f] = __builtin_amdgcn_mfma_f32_16x16x32_bf16(a1, b, acc[1][f], 0, 0, 0);
    }
  }
}

__device__ __forceinline__ void mma_gi(const short* As, const short* Ws, f32x4 acc[3]) {
  const int lane = threadIdx.x & 63, w = threadIdx.x >> 6;
  const int lr = lane & 15, lk = (lane >> 4) << 3;
  #pragma unroll
  for (int ks = 0; ks < 2; ++ks) {
    const int ko = ks*32 + lk; const int ca = ko >> 3;
    const int ra = w*16 + lr;
    short8 av = *(const short8*)&As[ra*64 + ((ca ^ (ra & 7)) << 3)];
    #pragma unroll
    for (int f = 0; f < 3; ++f) {
      const int rb = f*16 + lr;
      short8 bv = *(const short8*)&Ws[rb*64 + ((ca ^ (rb & 7)) << 3)];
      acc[f] = __builtin_amdgcn_mfma_f32_16x16x32_bf16(av, bv, acc[f], 0, 0, 0);
    }
  }
}

// ---------------- args ----------------
struct CArgs {
  char* ws;
  const float* enc; const float* act; const float* nq;
  const float* b_e; const float* b_ih; const float* b_hh;
  const float* b_q1; const float* b_q2;
  float* y1; float* y2; float* y5; float* y6;
};

// ---------------- per-step device tiles ----------------
__device__ void emb_tile(SMem& sm, const CArgs& A, int id, int t) {
  const int mi = id & 3, ni = id >> 2;          // 4 x 16 tiles (64x128)
  const int m0 = mi << 6, n0 = ni << 7;
  Aseg a{A.ws + O_POSTB, LD, LD, 0, (const char*)(A.act + (size_t)t*AD), TS*AD, 1, KE};
  f32x4 acc[2][4];
  for (int i=0;i<2;++i) for (int j=0;j<4;++j) acc[i][j] = z4();
  run_gemm<4>(sm, a, (const short*)(A.ws + O_WE), KE, m0, n0, HD, acc, 0, 320);
  epi_generic<4>(acc, m0, n0, HD, A.b_e, 1, nullptr, 0, (unsigned short*)(A.ws + O_EMB), HD);
}

// gh: 64x64 out tile, T4 counted-vmcnt depth-2 (r4-verified loop structure)
__device__ void gh_tile_pipe(SMemP& sm, const CArgs& A, int id) {
  const int xcd = id & 7, local = id >> 3;      // 48 locals per XCD
  const int mi = local & 3, nio = local >> 2;   // 4m x 12n
  const int m0 = mi << 6, n0 = xcd*768 + nio*64;
  const short* hB  = (const short*)(A.ws + O_HBF);
  const short* Whh = (const short*)(A.ws + O_WHH);
  f32x4 acc[2][2];
  for (int i=0;i<2;++i) for (int j=0;j<2;++j) acc[i][j] = z4();
  stage_pipe_rows(sm.A[0], hB, HD, m0, 0);   stage_pipe_rows(sm.W[0], Whh, HD, n0, 0);
  stage_pipe_rows(sm.A[1], hB, HD, m0, 64);  stage_pipe_rows(sm.W[1], Whh, HD, n0, 64);
  #pragma unroll 1
  for (int idx = 0; idx < 32; ++idx) {
    const int buf = idx % 3;
    if (idx + 2 < 32) {
      const int nb = (idx + 2) % 3;
      stage_pipe_rows(sm.A[nb], hB, HD, m0, (idx+2)*64);
      stage_pipe_rows(sm.W[nb], Whh, HD, n0, (idx+2)*64);
      asm volatile("s_waitcnt vmcnt(8)" ::: "memory");   // tile idx landed; 2 in flight
    } else if (idx + 1 < 32) {
      asm volatile("s_waitcnt vmcnt(4)" ::: "memory");
    } else {
      asm volatile("s_waitcnt vmcnt(0)" ::: "memory");
    }
    __builtin_amdgcn_s_barrier();
    __builtin_amdgcn_sched_barrier(0);
    mma_swz<2>(sm.A[buf], sm.W[buf], acc);
    asm volatile("s_waitcnt lgkmcnt(0)" ::: "memory");   // ds_reads done before buf reuse
    __builtin_amdgcn_sched_barrier(0);
    __builtin_amdgcn_s_barrier();
  }
  epi_generic<2>(acc, m0, n0, H3, A.b_hh, 0, (float*)(A.ws + O_GH), H3, nullptr, 0);
}

// gi: T4 counted-vmcnt depth-2 + fused GRU gates (r2 geometry, r4 loop structure)
__device__ void gi_tile_pipe(SMemP& sm, const CArgs& A, int id, int t) {
  const int xcd = id & 7, local = id >> 3;      // 64 locals per XCD
  const int mi = local & 3, jl = local >> 2;    // 4m x 16j (16-wide)
  const int m0 = mi << 6, j0 = xcd*256 + jl*16;
  const short* eB  = (const short*)(A.ws + O_EMB);
  const short* Wih = (const short*)(A.ws + O_WIH);
  f32x4 acc[3]; acc[0] = z4(); acc[1] = z4(); acc[2] = z4();
  stage_pipe_rows(sm.A[0], eB, HD, m0, 0);   stage_pipe_gi(sm.W[0], Wih, j0, 0);
  stage_pipe_rows(sm.A[1], eB, HD, m0, 64);  stage_pipe_gi(sm.W[1], Wih, j0, 64);
  #pragma unroll 1
  for (int idx = 0; idx < 32; ++idx) {
    const int buf = idx % 3;
    if (idx + 2 < 32) {
      const int nb = (idx + 2) % 3;
      stage_pipe_rows(sm.A[nb], eB, HD, m0, (idx+2)*64);
      stage_pipe_gi(sm.W[nb], Wih, j0, (idx+2)*64);
      asm volatile("s_waitcnt vmcnt(8)" ::: "memory");
    } else if (idx + 1 < 32) {
      asm volatile("s_waitcnt vmcnt(4)" ::: "memory");
    } else {
      asm volatile("s_waitcnt vmcnt(0)" ::: "memory");
    }
    __builtin_amdgcn_s_barrier();
    __builtin_amdgcn_sched_barrier(0);
    mma_gi(sm.A[buf], sm.W[buf], acc);
    asm volatile("s_waitcnt lgkmcnt(0)" ::: "memory");
    __builtin_amdgcn_sched_barrier(0);
    __builtin_amdgcn_s_barrier();
  }
  // fused GRU gates: lane holds (i_r,i_z,i_n) for its (m, j)
  const int lane = threadIdx.x & 63, w = threadIdx.x >> 6;
  const int lr = lane & 15;
  const int j = j0 + lr;
  float* hF = (float*)(A.ws + O_HF);
  unsigned short* hB = (unsigned short*)(A.ws + O_HBF);
  const float* gh = (const float*)(A.ws + O_GH);
  #pragma unroll
  for (int r = 0; r < 4; ++r) {
    const int m = m0 + w*16 + ((lane >> 4) << 2) + r;
    const float* g = gh + (size_t)m * H3;
    const float ir = acc[0][r] + A.b_ih[j]        + g[j];
    const float iz = acc[1][r] + A.b_ih[HD + j]   + g[HD + j];
    const float in_ = acc[2][r] + A.b_ih[2*HD + j];
    const float rr = sigm(ir), zz = sigm(iz);
    const float nn = tanh_f(in_ + rr * g[2*HD + j]);
    const float hv = (1.f - zz) * nn + zz * hF[(size_t)m*HD + j];
    hF[(size_t)m*HD + j] = hv;
    hB[(size_t)m*HD + j] = f2bf(hv);
    A.y2[(size_t)m * (TS*HD) + (size_t)t*HD + j] = hv;
  }
}

__device__ void q1_tile(SMem& sm, const CArgs& A, int id, int t) {
  const int s = id >> 3, rest = id & 7;         // split-K 16 x (4m x 2n)
  const int mi = rest & 3, ni = rest >> 2;
  const int m0 = mi << 6, n0 = ni << 7;
  Aseg a{A.ws + O_HBF, HD, HD, 0, (const char*)(A.enc + (size_t)t*ED), TS*ED, 1, KQ};
  f32x4 acc[2][4];
  for (int i=0;i<2;++i) for (int j=0;j<4;++j) acc[i][j] = z4();
  run_gemm<4>(sm, a, (const short*)(A.ws + O_WQ1), KQ, m0, n0, FD, acc, s*192, s*192+192);
  epi_generic<4>(acc, m0, n0, FD, nullptr, 0,
                 (float*)(A.ws + O_Q1P) + (size_t)s*NB*256, 256, nullptr, 0);
}

__device__ void q2_tile(SMem& sm, const CArgs& A, int id) {
  const int mi = id & 3, ni = id >> 2;
  const int m0 = mi << 6, n0 = ni << 7;
  f32x4 acc[2][4];
  for (int i=0;i<2;++i) for (int j=0;j<4;++j) acc[i][j] = z4();
  const short* W = (const short*)(A.ws + O_WQ2);
  for (int k0 = 0; k0 < 256; k0 += 64) {
    __syncthreads();
    stageA_red(sm.As, (const float*)(A.ws + O_Q1P), A.b_q1, m0, k0);
    stageW(sm.Ws, W, FD, n0, 128, FD, k0, FD);
    __syncthreads();
    mma_tile<4>(sm.As, sm.Ws, acc);
  }
  epi_generic<4>(acc, m0, n0, FD, A.b_q2, 1, nullptr, 0, (unsigned short*)(A.ws + O_Q2), FD);
}

__device__ void heads_tile(SMem& sm, const CArgs& A, int id, int t) {
  const int mi = id & 3, ni = id >> 2;
  const int m0 = mi << 6, n0 = ni << 7;
  Aseg a{A.ws + O_Q2, FD, FD, 0, nullptr, 0, 0, FD};
  f32x4 acc[2][4];
  for (int i=0;i<2;++i) for (int j=0;j<4;++j) acc[i][j] = z4();
  run_gemm<4>(sm, a, (const short*)(A.ws + O_WQMS), FD, m0, n0, 512, acc, 0, 256);
  epi_heads<4>(acc, m0, n0, (const float*)(A.ws + O_BQMS),
               A.nq + (size_t)t*LD, (long)TS*LD,
               A.y5 + (size_t)t*LD, A.y6 + (size_t)t*LD, A.y1 + (size_t)t*LD,
               (unsigned short*)(A.ws + O_POSTB));
}

// ---------------- per-step kernels (stream-ordered; r2 shape) ----------------
__global__ __launch_bounds__(256, 2) void k_step1(CArgs A, int t) {   // gh(t) + emb(t)
  __shared__ SMemU sm;
  if (blockIdx.x < 384) gh_tile_pipe(sm.p, A, blockIdx.x);
  else                  emb_tile(sm.legacy, A, blockIdx.x - 384, t);
}
__global__ __launch_bounds__(256, 2) void k_gi(CArgs A, int t) {      // gi + gates -> h(t)
  __shared__ SMemP sm;
  gi_tile_pipe(sm, A, blockIdx.x, t);
}
__global__ __launch_bounds__(256, 2) void k_q1(CArgs A, int t) {
  __shared__ SMem sm;
  q1_tile(sm, A, blockIdx.x, t);
}
__global__ __launch_bounds__(256, 2) void k_q2(CArgs A) {
  __shared__ SMem sm;
  q2_tile(sm, A, blockIdx.x);
}
__global__ __launch_bounds__(256, 2) void k_heads(CArgs A, int t) {
  __shared__ SMem sm;
  heads_tile(sm, A, blockIdx.x, t);
}

// ---------------- init: f32 -> bf16 weights, interleaves, state ----------------
__global__ void k_init(char* ws, const float* prevs, const float* prevh,
  const float* We, const float* Wih, const float* Whh,
  const float* Wp1, const float* Wp2, const float* Wpm, const float* Wps,
  const float* Wq1, const float* Wq2, const float* Wqm, const float* Wqs,
  const float* Wr1, const float* Wr2, const float* Wr3,
  const float* bpm, const float* bps, const float* bqm, const float* bqs) {
  const size_t stride = (size_t)gridDim.x * blockDim.x;
  for (size_t i = (size_t)blockIdx.x*blockDim.x + threadIdx.x; i < 12582912ull; i += stride) {
    ((unsigned short*)(ws + O_WIH))[i] = f2bf(Wih[i]);
    ((unsigned short*)(ws + O_WHH))[i] = f2bf(Whh[i]);
    if (i < 589824)  ((unsigned short*)(ws + O_WE))[i]  = f2bf(We[i]);
    if (i < 614400)  ((unsigned short*)(ws + O_WQ1))[i] = f2bf(Wq1[i]);
    if (i < 409600)  ((unsigned short*)(ws + O_WP1))[i] = f2bf(Wp1[i]);
    if (i < 460800)  ((unsigned short*)(ws + O_WR1))[i] = f2bf(Wr1[i]);
    if (i < 40000) {
      ((unsigned short*)(ws + O_WQ2))[i] = f2bf(Wq2[i]);
      ((unsigned short*)(ws + O_WP2))[i] = f2bf(Wp2[i]);
      ((unsigned short*)(ws + O_WR2))[i] = f2bf(Wr2[i]);
    }
    if (i < 200) ((unsigned short*)(ws + O_WR3))[i] = f2bf(Wr3[i]);
    if (i < 102400) {
      const int r = (int)(i / 200), c = (int)(i % 200);
      ((unsigned short*)(ws + O_WQMS))[i] = f2bf(((r & 1) ? Wqs : Wqm)[(r >> 1)*200 + c]);
      ((unsigned short*)(ws + O_WPMS))[i] = f2bf(((r & 1) ? Wps : Wpm)[(r >> 1)*200 + c]);
    }
    if (i < 512) {
      ((float*)(ws + O_BQMS))[i] = ((i & 1) ? bqs : bqm)[i >> 1];
      ((float*)(ws + O_BPMS))[i] = ((i & 1) ? bps : bpm)[i >> 1];
    }
    if (i < 65536) ((unsigned short*)(ws + O_POSTB))[i] = f2bf(prevs[i]);
    if (i < 524288) {
      ((unsigned short*)(ws + O_HBF))[i] = f2bf(prevh[i]);
      ((float*)(ws + O_HF))[i] = prevh[i];
    }
  }
}

// ---------------- post-loop batched prior/reward chains (M = 32768) ----------------
__global__ __launch_bounds__(256, 2) void k_big(int mode, char* ws,
  const float* y1, const float* y2, float* y0, float* y3, float* y4,
  const float* npn, const float* bp1, const float* bp2, const float* br1, const float* br2) {
  __shared__ SMem sm;
  if (mode == 2) { // prior heads + prior_s
    for (int tile = blockIdx.x; tile < 2048; tile += gridDim.x) {
      const int mi = tile >> 2, ni = tile & 3;
      const int m0 = mi << 6, n0 = ni << 7;
      Aseg a{ws + O_P2B, FD, FD, 0, nullptr, 0, 0, FD};
      f32x4 acc[2][4];
      for (int i=0;i<2;++i) for (int j=0;j<4;++j) acc[i][j] = z4();
      run_gemm<4>(sm, a, (const short*)(ws + O_WPMS), FD, m0, n0, 512, acc, 0, 256);
      epi_heads<4>(acc, m0, n0, (const float*)(ws + O_BPMS), npn, 256, y3, y4, y0, nullptr);
    }
    return;
  }
  for (int tile = blockIdx.x; tile < 1024; tile += gridDim.x) {
    const int mi = tile >> 1, ni = tile & 1;
    const int m0 = mi << 6, n0 = ni << 7;
    Aseg a; const short* W; const float* bias;
    if (mode == 0)      { a = {(const char*)y2, HD, HD, 1, nullptr, 0, 0, HD}; W = (const short*)(ws + O_WP1); bias = bp1; }
    else if (mode == 1) { a = {ws + O_P1B, FD, FD, 0, nullptr, 0, 0, FD};      W = (const short*)(ws + O_WP2); bias = bp2; }
    else if (mode == 3) { a = {(const char*)y1, LD, LD, 1, (const char*)y2, HD, 1, KR}; W = (const short*)(ws + O_WR1); bias = br1; }
    else                { a = {ws + O_P1B, FD, FD, 0, nullptr, 0, 0, FD};      W = (const short*)(ws + O_WR2); bias = br2; }
    f32x4 acc[2][4];
    for (int i=0;i<2;++i) for (int j=0;j<4;++j) acc[i][j] = z4();
    const int ke = (a.K + 63) & ~63;
    run_gemm<4>(sm, a, W, a.K, m0, n0, FD, acc, 0, ke);
    unsigned short* outp = (unsigned short*)(ws + ((mode == 0 || mode == 3) ? O_P1B : O_P2B));
    epi_generic<4>(acc, m0, n0, FD, bias, 1, nullptr, 0, outp, FD);
  }
}

__global__ void k_r3(char* ws, const float* br3, float* y7) {
  __shared__ float w3[200];
  for (int i = threadIdx.x; i < 200; i += 256) w3[i] = bf2f(((unsigned short*)(ws + O_WR3))[i]);
  __syncthreads();
  const int m = blockIdx.x * 256 + threadIdx.x;
  const unsigned short* r2 = (const unsigned short*)(ws + O_P2B) + (size_t)m * FD;
  float s = br3[0];
  for (int k = 0; k < FD; k += 8) {
    short8 v = *(const short8*)(r2 + k);
    #pragma unroll
    for (int j = 0; j < 8; ++j) s += bf2f((unsigned short)v[j]) * w3[k + j];
  }
  y7[m] = s;
}

// ---------------- host launcher ----------------
extern "C" void kernel_launch(void* const* d_in, const int* in_sizes, int n_in,
                              void* d_out, int out_size, void* d_ws, size_t ws_size,
                              hipStream_t stream) {
  (void)in_sizes; (void)n_in; (void)out_size; (void)ws_size;
  char* ws = (char*)d_ws;
  #define FIN(i) ((const float*)d_in[i])
  float* out = (float*)d_out;
  float* y0 = out + Y0; float* y1 = out + Y1; float* y2 = out + Y2; float* y3 = out + Y3;
  float* y4 = out + Y4; float* y5 = out + Y5; float* y6 = out + Y6; float* y7 = out + Y7;

  k_init<<<2048, 256, 0, stream>>>(ws, FIN(0), FIN(1), FIN(6), FIN(8), FIN(10),
    FIN(12), FIN(14), FIN(16), FIN(18), FIN(20), FIN(22), FIN(24), FIN(26),
    FIN(28), FIN(30), FIN(32), FIN(17), FIN(19), FIN(25), FIN(27));

  CArgs ca;
  ca.ws = ws; ca.enc = FIN(2); ca.act = FIN(3); ca.nq = FIN(5);
  ca.b_e = FIN(7); ca.b_ih = FIN(9); ca.b_hh = FIN(11); ca.b_q1 = FIN(21); ca.b_q2 = FIN(23);
  ca.y1 = y1; ca.y2 = y2; ca.y5 = y5; ca.y6 = y6;

  for (int t = 0; t < TS; ++t) {
    k_step1<<<448, 256, 0, stream>>>(ca, t);   // gh(t) [T4 pipelined] + emb(t)
    k_gi   <<<512, 256, 0, stream>>>(ca, t);   // gi [T4 pipelined] + gates -> h(t), y2
    k_q1   <<<128, 256, 0, stream>>>(ca, t);   // posterior l1 (split-K 16 partials)
    k_q2   <<<8,   256, 0, stream>>>(ca);      // reduce + l2
    k_heads<<<16,  256, 0, stream>>>(ca, t);   // heads -> post(t), y1,y5,y6
  }

  k_big<<<2048, 256, 0, stream>>>(0, ws, y1, y2, y0, y3, y4, FIN(4), FIN(13), FIN(15), FIN(29), FIN(31));
  k_big<<<2048, 256, 0, stream>>>(1, ws, y1, y2, y0, y3, y4, FIN(4), FIN(13), FIN(15), FIN(29), FIN(31));
  k_big<<<2048, 256, 0, stream>>>(2, ws, y1, y2, y0, y3, y4, FIN(4), FIN(13), FIN(15), FIN(29), FIN(31));
  k_big<<<2048, 256, 0, stream>>>(3, ws, y1, y2, y0, y3, y4, FIN(4), FIN(13), FIN(15), FIN(29), FIN(31));
  k_big<<<2048, 256, 0, stream>>>(4, ws, y1, y2, y0, y3, y4, FIN(4), FIN(13), FIN(15), FIN(29), FIN(31));
  k_r3<<<128, 256, 0, stream>>>(ws, FIN(33), y7);
}

// Round 9
// 15073.654 us; speedup vs baseline: 1.7010x; 1.0258x over previous
//
#include <hip/hip_runtime.h>
#include <hip/hip_bf16.h>

// ---------------- problem constants ----------------
#define TS 128
#define NB 256
#define HD 2048
#define H3 6144
#define LD 256
#define ED 1024
#define AD 32
#define FD 200
#define KE 288     // L + A
#define KQ 3072    // H + E
#define KR 2304    // L + H
#define MT 32768   // NB * TS

typedef __attribute__((ext_vector_type(8))) short short8;
typedef __attribute__((ext_vector_type(4))) float f32x4;

// ---------------- workspace layout (r2-identical) ----------------
constexpr size_t alup(size_t x) { return (x + 255) & ~size_t(255); }
constexpr size_t O_WE   = 0;
constexpr size_t O_WIH  = alup(O_WE   + 2ull*2048*288);
constexpr size_t O_WHH  = alup(O_WIH  + 2ull*6144*2048);
constexpr size_t O_WQ1  = alup(O_WHH  + 2ull*6144*2048);
constexpr size_t O_WQ2  = alup(O_WQ1  + 2ull*200*3072);
constexpr size_t O_WQMS = alup(O_WQ2  + 2ull*200*200);   // interleaved [qm0,qs0,...] rows
constexpr size_t O_WP1  = alup(O_WQMS + 2ull*512*200);
constexpr size_t O_WP2  = alup(O_WP1  + 2ull*200*2048);
constexpr size_t O_WPMS = alup(O_WP2  + 2ull*200*200);
constexpr size_t O_WR1  = alup(O_WPMS + 2ull*512*200);
constexpr size_t O_WR2  = alup(O_WR1  + 2ull*200*2304);
constexpr size_t O_WR3  = alup(O_WR2  + 2ull*200*200);
constexpr size_t O_BQMS = alup(O_WR3  + 2ull*200);       // f32[512] interleaved bias
constexpr size_t O_BPMS = alup(O_BQMS + 4ull*512);
constexpr size_t O_POSTB= alup(O_BPMS + 4ull*512);       // bf16 [256][256]
constexpr size_t O_HBF  = alup(O_POSTB+ 2ull*NB*LD);     // bf16 [256][2048]
constexpr size_t O_HF   = alup(O_HBF  + 2ull*NB*HD);     // f32  [256][2048]
constexpr size_t O_EMB  = alup(O_HF   + 4ull*NB*HD);     // bf16 [256][2048]
constexpr size_t O_GH   = alup(O_EMB  + 2ull*NB*HD);     // f32  [256][6144]
constexpr size_t O_Q1P  = alup(O_GH   + 4ull*NB*H3);     // f32  [4][256][256] split-K partials
constexpr size_t O_Q2   = alup(O_Q1P  + 4ull*16*NB*256); // (unused)
constexpr size_t O_BARF = alup(O_Q2   + 2ull*NB*FD);
constexpr size_t O_BARC = alup(O_BARF + 4ull*(64*32+64));
constexpr size_t O_P1B  = alup(O_BARC + 4ull*(16*32+64));// bf16 [32768][200]
constexpr size_t O_P2B  = alup(O_P1B  + 2ull*(size_t)MT*FD);
constexpr size_t O_END  = alup(O_P2B  + 2ull*(size_t)MT*FD); // ~96.6 MB

// output offsets (f32 elements)
#define Y0 0ull
#define Y1 8388608ull
#define Y2 16777216ull
#define Y3 83886080ull
#define Y4 92274688ull
#define Y5 100663296ull
#define Y6 109051904ull
#define Y7 117440512ull

// ---------------- small helpers ----------------
__device__ __forceinline__ unsigned short f2bf(float f) {
  union { float f; unsigned u; } v; v.f = f;
  unsigned r = v.u + 0x7fffu + ((v.u >> 16) & 1u);
  return (unsigned short)(r >> 16);
}
__device__ __forceinline__ float bf2f(unsigned short u) {
  union { unsigned u; float f; } v; v.u = ((unsigned)u) << 16;
  return v.f;
}
__device__ __forceinline__ float sigm(float x) { return 1.f / (1.f + __expf(-x)); }
__device__ __forceinline__ float tanh_f(float x) {
  float e = __expf(-2.f * fabsf(x));
  float t = (1.f - e) / (1.f + e);
  return x >= 0.f ? t : -t;
}
__device__ __forceinline__ float softp(float x) { return x > 15.f ? x : log1pf(__expf(x)); }
__device__ __forceinline__ f32x4 z4() { f32x4 z; z[0]=0.f; z[1]=0.f; z[2]=0.f; z[3]=0.f; return z; }

struct SMem {
  alignas(16) short As[64*72];   // legacy reg-staged path
  alignas(16) short Ws[128*72];
};
struct SMemP {                   // pipelined gload_lds path: linear, TRIPLE-buffered (T4)
  alignas(16) short A[3][64*64];
  alignas(16) short W[3][64*64];
};
union SMemU { SMemP p; SMem legacy; };
struct SMemQH {                  // k_q2h: legacy bufs + resident q2 band
  alignas(16) short As[64*72];
  alignas(16) short Ws[128*72];
  alignas(16) short q2l[64*264]; // 64-row band, pad 264
};

struct Aseg {  // A operand: up to 2 concatenated segments, each f32 or bf16
  const char* p0; int lda0; int K0; int f0;
  const char* p1; int lda1; int f1;
  int K;
};

// ---------------- legacy reg-staged path (r1/r2-verified) ----------------
__device__ __forceinline__ void stageA(short* As, const Aseg& a, int m0, int k0) {
  const int t = threadIdx.x;
  const int row = t >> 2;
  const int cb = (t & 3) << 4;
  #pragma unroll
  for (int i = 0; i < 2; ++i) {
    const int c = cb + i * 8;
    const int gk = k0 + c;
    short8 v = {};
    if (gk < a.K) {
      const char* p; long idx; int isf;
      if (gk < a.K0) { p = a.p0; idx = (long)(m0 + row) * a.lda0 + gk; isf = a.f0; }
      else           { p = a.p1; idx = (long)(m0 + row) * a.lda1 + (gk - a.K0); isf = a.f1; }
      if (isf) {
        const float* pf = (const float*)p + idx;
        #pragma unroll
        for (int j = 0; j < 8; ++j) v[j] = (short)f2bf(pf[j]);
      } else {
        v = *(const short8*)((const short*)p + idx);
      }
    }
    *(short8*)&As[row*72 + c] = v;
  }
}

__device__ __forceinline__ void stageW(short* Ws, const short* W, int ldw, int n0, int BN,
                                       int Nmax, int k0, int K) {
  const int nch = BN << 3;
  for (int id = threadIdx.x; id < nch; id += 256) {
    const int row = id >> 3;
    const int c = (id & 7) << 3;
    const int gk = k0 + c;
    int gr = n0 + row; gr = gr < Nmax ? gr : Nmax - 1;
    short8 v = {};
    if (gk < K) v = *(const short8*)(W + (long)gr * ldw + gk);
    *(short8*)&Ws[row*72 + c] = v;
  }
}

// q2 A-stage: A = relu(sum_s q1_partial[s] + bq1), K=200, 4 slices (r3/r7-verified)
__device__ __forceinline__ void stageA_red4(short* As, const float* q1p, const float* bq1,
                                            int m0, int k0) {
  const int t = threadIdx.x;
  const int row = t >> 2;
  const int cb = (t & 3) << 4;
  #pragma unroll
  for (int i = 0; i < 2; ++i) {
    const int c = cb + i * 8;
    const int gk = k0 + c;
    short8 v = {};
    if (gk < FD) {
      float s[8];
      #pragma unroll
      for (int j = 0; j < 8; ++j) s[j] = bq1[gk + j];
      #pragma unroll
      for (int ss = 0; ss < 4; ++ss) {
        const float* p = q1p + (size_t)ss * NB * 256 + (size_t)(m0 + row) * 256 + gk;
        #pragma unroll
        for (int j = 0; j < 8; ++j) s[j] += p[j];
      }
      #pragma unroll
      for (int j = 0; j < 8; ++j) v[j] = (short)f2bf(fmaxf(s[j], 0.f));
    }
    *(short8*)&As[row*72 + c] = v;
  }
}

template<int NF>
__device__ __forceinline__ void mma_tile(const short* As, const short* Ws, f32x4 acc[2][NF]) {
  const int lane = threadIdx.x & 63;
  const int w = threadIdx.x >> 6;
  const int wm = (w >> 1) << 5;
  const int wn = (w & 1) * (NF << 4);
  const int lr = lane & 15, lk = (lane >> 4) << 3;
  #pragma unroll
  for (int ks = 0; ks < 2; ++ks) {
    const int ko = ks * 32 + lk;
    short8 a0 = *(const short8*)&As[(wm + lr)*72 + ko];
    short8 a1 = *(const short8*)&As[(wm + 16 + lr)*72 + ko];
    #pragma unroll
    for (int f = 0; f < NF; ++f) {
      short8 b = *(const short8*)&Ws[(wn + f*16 + lr)*72 + ko];
      acc[0][f] = __builtin_amdgcn_mfma_f32_16x16x32_bf16(a0, b, acc[0][f], 0, 0, 0);
      acc[1][f] = __builtin_amdgcn_mfma_f32_16x16x32_bf16(a1, b, acc[1][f], 0, 0, 0);
    }
  }
}

// mma variant: A resident in q2l [64][264], full-K; W staged per-64 chunk (r6-verified)
template<int NF>
__device__ __forceinline__ void mma_q2l(const short* q2l, const short* Ws, int k0,
                                        f32x4 acc[2][NF]) {
  const int lane = threadIdx.x & 63;
  const int w = threadIdx.x >> 6;
  const int wm = (w >> 1) << 5;
  const int wn = (w & 1) * (NF << 4);
  const int lr = lane & 15, lk = (lane >> 4) << 3;
  #pragma unroll
  for (int ks = 0; ks < 2; ++ks) {
    const int kl = ks * 32 + lk;
    short8 a0 = *(const short8*)&q2l[(wm + lr)*264 + k0 + kl];
    short8 a1 = *(const short8*)&q2l[(wm + 16 + lr)*264 + k0 + kl];
    #pragma unroll
    for (int f = 0; f < NF; ++f) {
      short8 b = *(const short8*)&Ws[(wn + f*16 + lr)*72 + kl];
      acc[0][f] = __builtin_amdgcn_mfma_f32_16x16x32_bf16(a0, b, acc[0][f], 0, 0, 0);
      acc[1][f] = __builtin_amdgcn_mfma_f32_16x16x32_bf16(a1, b, acc[1][f], 0, 0, 0);
    }
  }
}

template<int NF>
__device__ void run_gemm(SMem& sm, const Aseg& a, const short* W, int ldw, int m0, int n0,
                         int Nmax, f32x4 acc[2][NF], int kb, int ke) {
  for (int k0 = kb; k0 < ke; k0 += 64) {
    __syncthreads();
    stageA(sm.As, a, m0, k0);
    stageW(sm.Ws, W, ldw, n0, NF*32, Nmax, k0, a.K);
    __syncthreads();
    mma_tile<NF>(sm.As, sm.Ws, acc);
  }
}

// C/D layout (m89-verified): col = lane&15, row = (lane>>4)*4 + reg
template<int NF>
__device__ void epi_generic(f32x4 acc[2][NF], int m0, int n0, int Nmax, const float* bias,
                            int relu, float* outF, long rsF, unsigned short* outB, int rsB) {
  const int lane = threadIdx.x & 63;
  const int w = threadIdx.x >> 6;
  const int wm = (w >> 1) << 5, wn = (w & 1) * (NF << 4);
  #pragma unroll
  for (int mt = 0; mt < 2; ++mt)
  #pragma unroll
  for (int f = 0; f < NF; ++f)
  #pragma unroll
  for (int r = 0; r < 4; ++r) {
    const int m = m0 + wm + mt*16 + ((lane >> 4) << 2) + r;
    const int n = n0 + wn + f*16 + (lane & 15);
    if (n < Nmax) {
      float v = acc[mt][f][r];
      if (bias) v += bias[n];
      if (relu) v = fmaxf(v, 0.f);
      if (outF) outF[(long)m * rsF + n] = v;
      if (outB) outB[(long)m * rsB + n] = f2bf(v);
    }
  }
}

// q2 epilogue -> LDS band [64][264] (local rows), relu+bias (r6-verified)
template<int NF>
__device__ void epi_q2l(f32x4 acc[2][NF], int n0, const float* bias, short* q2l) {
  const int lane = threadIdx.x & 63;
  const int w = threadIdx.x >> 6;
  const int wm = (w >> 1) << 5, wn = (w & 1) * (NF << 4);
  #pragma unroll
  for (int mt = 0; mt < 2; ++mt)
  #pragma unroll
  for (int f = 0; f < NF; ++f)
  #pragma unroll
  for (int r = 0; r < 4; ++r) {
    const int ml = wm + mt*16 + ((lane >> 4) << 2) + r;
    const int n = n0 + wn + f*16 + (lane & 15);
    if (n < FD) {
      float v = fmaxf(acc[mt][f][r] + bias[n], 0.f);
      q2l[ml*264 + n] = (short)f2bf(v);
    }
  }
}

template<int NF>
__device__ void epi_heads(f32x4 acc[2][NF], int m0, int n0, const float* biasI,
                          const float* noise, long rs, float* outMu, float* outStd,
                          float* outComb, unsigned short* postbf) {
  const int lane = threadIdx.x & 63;
  const int w = threadIdx.x >> 6;
  const int wm = (w >> 1) << 5, wn = (w & 1) * (NF << 4);
  #pragma unroll
  for (int mt = 0; mt < 2; ++mt)
  #pragma unroll
  for (int f = 0; f < NF; ++f)
  #pragma unroll
  for (int r = 0; r < 4; ++r) {
    const int m = m0 + wm + mt*16 + ((lane >> 4) << 2) + r;
    const int n = n0 + wn + f*16 + (lane & 15);
    float v = acc[mt][f][r] + biasI[n];
    if (n & 1) v = softp(v) + 0.1f;               // std lanes
    float partner = __shfl_xor(v, 1);
    const int l = n >> 1;
    if (n & 1) {
      outStd[(long)m * rs + l] = v;
    } else {
      outMu[(long)m * rs + l] = v;
      float comb = v + partner * noise[(long)m * rs + l];
      outComb[(long)m * rs + l] = comb;
      if (postbf) postbf[m * LD + l] = f2bf(comb);
    }
  }
}

// ---------------- pipelined gload_lds path ----------------
__device__ __forceinline__ void gl_lds16(const void* g, void* l) {
  __builtin_amdgcn_global_load_lds(
      (const __attribute__((address_space(1))) unsigned int*)g,
      (__attribute__((address_space(3))) unsigned int*)l, 16, 0, 0);
}

// stage a 64x64 bf16 tile: LDS linear [64][64]; global source chunk XOR-swizzled (rule #21)
__device__ __forceinline__ void stage_pipe_rows(short* dst, const short* g, long ldw,
                                                int rbase, int k0) {
  const int w = threadIdx.x >> 6, l = threadIdx.x & 63;
  #pragma unroll
  for (int i = 0; i < 2; ++i) {
    const int inst = w*2 + i;
    const int row = inst*8 + (l >> 3);
    const int sc = (l & 7) ^ (row & 7);
    gl_lds16(g + (long)(rbase + row) * ldw + k0 + sc*8, dst + inst*512);
  }
}
// gi-slice W rows: 3 gates x 16 j-rows (rows 48-63 duplicate gate0; unused by MFMA)
__device__ __forceinline__ void stage_pipe_gi(short* dst, const short* W, int j0, int k0) {
  const int w = threadIdx.x >> 6, l = threadIdx.x & 63;
  #pragma unroll
  for (int i = 0; i < 2; ++i) {
    const int inst = w*2 + i;
    const int row = inst*8 + (l >> 3);
    const int g = (row >> 4) % 3;
    const int sc = (l & 7) ^ (row & 7);
    gl_lds16(W + (long)(g*2048 + j0 + (row & 15)) * 2048 + k0 + sc*8, dst + inst*512);
  }
}

template<int NF>
__device__ __forceinline__ void mma_swz(const short* As, const short* Ws, f32x4 acc[2][NF]) {
  const int lane = threadIdx.x & 63, w = threadIdx.x >> 6;
  const int wm = (w >> 1) << 5, wn = (w & 1) * (NF << 4);
  const int lr = lane & 15, lk = (lane >> 4) << 3;
  #pragma unroll
  for (int ks = 0; ks < 2; ++ks) {
    const int ko = ks*32 + lk; const int ca = ko >> 3;
    const int ra0 = wm + lr, ra1 = wm + 16 + lr;
    short8 a0 = *(const short8*)&As[ra0*64 + ((ca ^ (ra0 & 7)) << 3)];
    short8 a1 = *(const short8*)&As[ra1*64 + ((ca ^ (ra1 & 7)) << 3)];
    #pragma unroll
    for (int f = 0; f < NF; ++f) {
      const int rb = wn + f*16 + lr;
      short8 b = *(const short8*)&Ws[rb*64 + ((ca ^ (rb & 7)) << 3)];
      acc[0][f] = __builtin_amdgcn_mfma_f32_16x16x32_bf16(a0, b, acc[0][f], 0, 0, 0);
      acc[1][f] = __builtin_amdgcn_mfma_f32_16x16x32_bf16(a1, b, acc[1][f], 0, 0, 0);
    }
  }
}

__device__ __forceinline__ void mma_gi(const short* As, const short* Ws, f32x4 acc[3]) {
  const int lane = threadIdx.x & 63, w = threadIdx.x >> 6;
  const int lr = lane & 15, lk = (lane >> 4) << 3;
  #pragma unroll
  for (int ks = 0; ks < 2; ++ks) {
    const int ko = ks*32 + lk; const int ca = ko >> 3;
    const int ra = w*16 + lr;
    short8 av = *(const short8*)&As[ra*64 + ((ca ^ (ra & 7)) << 3)];
    #pragma unroll
    for (int f = 0; f < 3; ++f) {
      const int rb = f*16 + lr;
      short8 bv = *(const short8*)&Ws[rb*64 + ((ca ^ (rb & 7)) << 3)];
      acc[f] = __builtin_amdgcn_mfma_f32_16x16x32_bf16(av, bv, acc[f], 0, 0, 0);
    }
  }
}

// ---------------- args ----------------
struct CArgs {
  char* ws;
  const float* enc; const float* act; const float* nq;
  const float* b_e; const float* b_ih; const float* b_hh;
  const float* b_q1; const float* b_q2;
  float* y1; float* y2; float* y5; float* y6;
};

// ---------------- per-step device tiles ----------------
__device__ void emb_tile(SMem& sm, const CArgs& A, int id, int t) {
  const int mi = id & 3, ni = id >> 2;          // 4 x 16 tiles (64x128)
  const int m0 = mi << 6, n0 = ni << 7;
  Aseg a{A.ws + O_POSTB, LD, LD, 0, (const char*)(A.act + (size_t)t*AD), TS*AD, 1, KE};
  f32x4 acc[2][4];
  for (int i=0;i<2;++i) for (int j=0;j<4;++j) acc[i][j] = z4();
  run_gemm<4>(sm, a, (const short*)(A.ws + O_WE), KE, m0, n0, HD, acc, 0, 320);
  epi_generic<4>(acc, m0, n0, HD, A.b_e, 1, nullptr, 0, (unsigned short*)(A.ws + O_EMB), HD);
}

// gh: 64x64 out tile, T4 counted-vmcnt depth-2 (r8-verified)
__device__ void gh_tile_pipe(SMemP& sm, const CArgs& A, int id) {
  const int xcd = id & 7, local = id >> 3;      // 48 locals per XCD
  const int mi = local & 3, nio = local >> 2;   // 4m x 12n
  const int m0 = mi << 6, n0 = xcd*768 + nio*64;
  const short* hB  = (const short*)(A.ws + O_HBF);
  const short* Whh = (const short*)(A.ws + O_WHH);
  f32x4 acc[2][2];
  for (int i=0;i<2;++i) for (int j=0;j<2;++j) acc[i][j] = z4();
  stage_pipe_rows(sm.A[0], hB, HD, m0, 0);   stage_pipe_rows(sm.W[0], Whh, HD, n0, 0);
  stage_pipe_rows(sm.A[1], hB, HD, m0, 64);  stage_pipe_rows(sm.W[1], Whh, HD, n0, 64);
  #pragma unroll 1
  for (int idx = 0; idx < 32; ++idx) {
    const int buf = idx % 3;
    if (idx + 2 < 32) {
      const int nb = (idx + 2) % 3;
      stage_pipe_rows(sm.A[nb], hB, HD, m0, (idx+2)*64);
      stage_pipe_rows(sm.W[nb], Whh, HD, n0, (idx+2)*64);
      asm volatile("s_waitcnt vmcnt(8)" ::: "memory");   // tile idx landed; 2 in flight
    } else if (idx + 1 < 32) {
      asm volatile("s_waitcnt vmcnt(4)" ::: "memory");
    } else {
      asm volatile("s_waitcnt vmcnt(0)" ::: "memory");
    }
    __builtin_amdgcn_s_barrier();
    __builtin_amdgcn_sched_barrier(0);
    mma_swz<2>(sm.A[buf], sm.W[buf], acc);
    asm volatile("s_waitcnt lgkmcnt(0)" ::: "memory");   // ds_reads done before buf reuse
    __builtin_amdgcn_sched_barrier(0);
    __builtin_amdgcn_s_barrier();
  }
  epi_generic<2>(acc, m0, n0, H3, A.b_hh, 0, (float*)(A.ws + O_GH), H3, nullptr, 0);
}

// gi: T4 counted-vmcnt depth-2 + fused GRU gates (r8-verified)
__device__ void gi_tile_pipe(SMemP& sm, const CArgs& A, int id, int t) {
  const int xcd = id & 7, local = id >> 3;      // 64 locals per XCD
  const int mi = local & 3, jl = local >> 2;    // 4m x 16j (16-wide)
  const int m0 = mi << 6, j0 = xcd*256 + jl*16;
  const short* eB  = (const short*)(A.ws + O_EMB);
  const short* Wih = (const short*)(A.ws + O_WIH);
  f32x4 acc[3]; acc[0] = z4(); acc[1] = z4(); acc[2] = z4();
  stage_pipe_rows(sm.A[0], eB, HD, m0, 0);   stage_pipe_gi(sm.W[0], Wih, j0, 0);
  stage_pipe_rows(sm.A[1], eB, HD, m0, 64);  stage_pipe_gi(sm.W[1], Wih, j0, 64);
  #pragma unroll 1
  for (int idx = 0; idx < 32; ++idx) {
    const int buf = idx % 3;
    if (idx + 2 < 32) {
      const int nb = (idx + 2) % 3;
      stage_pipe_rows(sm.A[nb], eB, HD, m0, (idx+2)*64);
      stage_pipe_gi(sm.W[nb], Wih, j0, (idx+2)*64);
      asm volatile("s_waitcnt vmcnt(8)" ::: "memory");
    } else if (idx + 1 < 32) {
      asm volatile("s_waitcnt vmcnt(4)" ::: "memory");
    } else {
      asm volatile("s_waitcnt vmcnt(0)" ::: "memory");
    }
    __builtin_amdgcn_s_barrier();
    __builtin_amdgcn_sched_barrier(0);
    mma_gi(sm.A[buf], sm.W[buf], acc);
    asm volatile("s_waitcnt lgkmcnt(0)" ::: "memory");
    __builtin_amdgcn_sched_barrier(0);
    __builtin_amdgcn_s_barrier();
  }
  // fused GRU gates: lane holds (i_r,i_z,i_n) for its (m, j)
  const int lane = threadIdx.x & 63, w = threadIdx.x >> 6;
  const int lr = lane & 15;
  const int j = j0 + lr;
  float* hF = (float*)(A.ws + O_HF);
  unsigned short* hB = (unsigned short*)(A.ws + O_HBF);
  const float* gh = (const float*)(A.ws + O_GH);
  #pragma unroll
  for (int r = 0; r < 4; ++r) {
    const int m = m0 + w*16 + ((lane >> 4) << 2) + r;
    const float* g = gh + (size_t)m * H3;
    const float ir = acc[0][r] + A.b_ih[j]        + g[j];
    const float iz = acc[1][r] + A.b_ih[HD + j]   + g[HD + j];
    const float in_ = acc[2][r] + A.b_ih[2*HD + j];
    const float rr = sigm(ir), zz = sigm(iz);
    const float nn = tanh_f(in_ + rr * g[2*HD + j]);
    const float hv = (1.f - zz) * nn + zz * hF[(size_t)m*HD + j];
    hF[(size_t)m*HD + j] = hv;
    hB[(size_t)m*HD + j] = f2bf(hv);
    A.y2[(size_t)m * (TS*HD) + (size_t)t*HD + j] = hv;
  }
}

// q1 split-K 4 (r3/r7-verified): 32 wgs = 4 slices x (4m x 2n), 12 iters each
__device__ void q1_tile4(SMem& sm, const CArgs& A, int id, int t) {
  const int s = id >> 3, rest = id & 7;
  const int mi = rest & 3, ni = rest >> 2;
  const int m0 = mi << 6, n0 = ni << 7;
  Aseg a{A.ws + O_HBF, HD, HD, 0, (const char*)(A.enc + (size_t)t*ED), TS*ED, 1, KQ};
  f32x4 acc[2][4];
  for (int i=0;i<2;++i) for (int j=0;j<4;++j) acc[i][j] = z4();
  run_gemm<4>(sm, a, (const short*)(A.ws + O_WQ1), KQ, m0, n0, FD, acc, s*768, s*768+768);
  epi_generic<4>(acc, m0, n0, FD, nullptr, 0,
                 (float*)(A.ws + O_Q1P) + (size_t)s*NB*256, 256, nullptr, 0);
}

// ---------------- per-step kernels (stream-ordered, 4/step) ----------------
__global__ __launch_bounds__(256, 2) void k_step1(CArgs A, int t) {   // prologue only
  __shared__ SMemU sm;
  if (blockIdx.x < 384) gh_tile_pipe(sm.p, A, blockIdx.x);
  else                  emb_tile(sm.legacy, A, blockIdx.x - 384, t);
}
__global__ __launch_bounds__(256, 2) void k_gi(CArgs A, int t) {      // gi + gates -> h(t)
  __shared__ SMemP sm;
  gi_tile_pipe(sm, A, blockIdx.x, t);
}
// k_mid: q1(t) [32 wgs, split-K 4] || gh(t+1) [384 wgs]
__global__ __launch_bounds__(256, 2) void k_mid(CArgs A, int t) {
  __shared__ SMemU sm;
  if (blockIdx.x < 32) { q1_tile4(sm.legacy, A, blockIdx.x, t); return; }
  if (t + 1 >= TS) return;
  gh_tile_pipe(sm.p, A, blockIdx.x - 32);
}
// fused q2 + heads: 16 wgs = 4 m-bands x 4 head-quarters (r6 structure, r7 hoisted-A,
// cheap 4-slice reduce). Each wg: band q2 (redundant x4, light) -> LDS; heads quarter.
__global__ __launch_bounds__(256, 2) void k_q2h(CArgs A, int t) {
  __shared__ SMemQH sm;
  const int id = blockIdx.x;
  const int mi = id & 3, qi = id >> 2;
  const int m0 = mi << 6;

  // phase 1: q2 band = relu(q1_red4 @ Wq2^T + bq2) -> q2l [64][264]; A staged once per k0
  const short* Wq2 = (const short*)(A.ws + O_WQ2);
  {
    f32x4 acc0[2][4], acc1[2][4];
    for (int i=0;i<2;++i) for (int j=0;j<4;++j) { acc0[i][j] = z4(); acc1[i][j] = z4(); }
    for (int k0 = 0; k0 < 256; k0 += 64) {
      __syncthreads();
      stageA_red4(sm.As, (const float*)(A.ws + O_Q1P), A.b_q1, m0, k0);
      stageW(sm.Ws, Wq2, FD, 0, 128, FD, k0, FD);
      __syncthreads();
      mma_tile<4>(sm.As, sm.Ws, acc0);
      __syncthreads();
      stageW(sm.Ws, Wq2, FD, 128, 128, FD, k0, FD);
      __syncthreads();
      mma_tile<4>(sm.As, sm.Ws, acc1);
    }
    epi_q2l<4>(acc0, 0, A.b_q2, sm.q2l);
    epi_q2l<4>(acc1, 128, A.b_q2, sm.q2l);
  }
  // zero pad cols 200..263
  for (int i = threadIdx.x; i < 64*64; i += 256)
    sm.q2l[(i >> 6)*264 + 200 + (i & 63)] = 0;
  __syncthreads();

  // phase 2: heads quarter n0 = qi*128, K=256 (A zeros >=200, W masked at 200)
  const short* Wqms = (const short*)(A.ws + O_WQMS);
  f32x4 acc[2][4];
  for (int i=0;i<2;++i) for (int j=0;j<4;++j) acc[i][j] = z4();
  for (int k0 = 0; k0 < 256; k0 += 64) {
    __syncthreads();
    stageW(sm.Ws, Wqms, FD, qi*128, 128, 512, k0, FD);
    __syncthreads();
    mma_q2l<4>(sm.q2l, sm.Ws, k0, acc);
  }
  epi_heads<4>(acc, m0, qi*128, (const float*)(A.ws + O_BQMS),
               A.nq + (size_t)t*LD, (long)TS*LD,
               A.y5 + (size_t)t*LD, A.y6 + (size_t)t*LD, A.y1 + (size_t)t*LD,
               (unsigned short*)(A.ws + O_POSTB));
}
// standalone emb(t) (r3-verified tile): 64 wgs
__global__ __launch_bounds__(256, 2) void k_emb(CArgs A, int t) {
  __shared__ SMem sm;
  emb_tile(sm, A, blockIdx.x, t);
}

// ---------------- init: f32 -> bf16 weights, interleaves, state ----------------
__global__ void k_init(char* ws, const float* prevs, const float* prevh,
  const float* We, const float* Wih, const float* Whh,
  const float* Wp1, const float* Wp2, const float* Wpm, const float* Wps,
  const float* Wq1, const float* Wq2, const float* Wqm, const float* Wqs,
  const float* Wr1, const float* Wr2, const float* Wr3,
  const float* bpm, const float* bps, const float* bqm, const float* bqs) {
  const size_t stride = (size_t)gridDim.x * blockDim.x;
  for (size_t i = (size_t)blockIdx.x*blockDim.x + threadIdx.x; i < 12582912ull; i += stride) {
    ((unsigned short*)(ws + O_WIH))[i] = f2bf(Wih[i]);
    ((unsigned short*)(ws + O_WHH))[i] = f2bf(Whh[i]);
    if (i < 589824)  ((unsigned short*)(ws + O_WE))[i]  = f2bf(We[i]);
    if (i < 614400)  ((unsigned short*)(ws + O_WQ1))[i] = f2bf(Wq1[i]);
    if (i < 409600)  ((unsigned short*)(ws + O_WP1))[i] = f2bf(Wp1[i]);
    if (i < 460800)  ((unsigned short*)(ws + O_WR1))[i] = f2bf(Wr1[i]);
    if (i < 40000) {
      ((unsigned short*)(ws + O_WQ2))[i] = f2bf(Wq2[i]);
      ((unsigned short*)(ws + O_WP2))[i] = f2bf(Wp2[i]);
      ((unsigned short*)(ws + O_WR2))[i] = f2bf(Wr2[i]);
    }
    if (i < 200) ((unsigned short*)(ws + O_WR3))[i] = f2bf(Wr3[i]);
    if (i < 102400) {
      const int r = (int)(i / 200), c = (int)(i % 200);
      ((unsigned short*)(ws + O_WQMS))[i] = f2bf(((r & 1) ? Wqs : Wqm)[(r >> 1)*200 + c]);
      ((unsigned short*)(ws + O_WPMS))[i] = f2bf(((r & 1) ? Wps : Wpm)[(r >> 1)*200 + c]);
    }
    if (i < 512) {
      ((float*)(ws + O_BQMS))[i] = ((i & 1) ? bqs : bqm)[i >> 1];
      ((float*)(ws + O_BPMS))[i] = ((i & 1) ? bps : bpm)[i >> 1];
    }
    if (i < 65536) ((unsigned short*)(ws + O_POSTB))[i] = f2bf(prevs[i]);
    if (i < 524288) {
      ((unsigned short*)(ws + O_HBF))[i] = f2bf(prevh[i]);
      ((float*)(ws + O_HF))[i] = prevh[i];
    }
  }
}

// ---------------- post-loop batched prior/reward chains (M = 32768) ----------------
__global__ __launch_bounds__(256, 2) void k_big(int mode, char* ws,
  const float* y1, const float* y2, float* y0, float* y3, float* y4,
  const float* npn, const float* bp1, const float* bp2, const float* br1, const float* br2) {
  __shared__ SMem sm;
  if (mode == 2) { // prior heads + prior_s
    for (int tile = blockIdx.x; tile < 2048; tile += gridDim.x) {
      const int mi = tile >> 2, ni = tile & 3;
      const int m0 = mi << 6, n0 = ni << 7;
      Aseg a{ws + O_P2B, FD, FD, 0, nullptr, 0, 0, FD};
      f32x4 acc[2][4];
      for (int i=0;i<2;++i) for (int j=0;j<4;++j) acc[i][j] = z4();
      run_gemm<4>(sm, a, (const short*)(ws + O_WPMS), FD, m0, n0, 512, acc, 0, 256);
      epi_heads<4>(acc, m0, n0, (const float*)(ws + O_BPMS), npn, 256, y3, y4, y0, nullptr);
    }
    return;
  }
  for (int tile = blockIdx.x; tile < 1024; tile += gridDim.x) {
    const int mi = tile >> 1, ni = tile & 1;
    const int m0 = mi << 6, n0 = ni << 7;
    Aseg a; const short* W; const float* bias;
    if (mode == 0)      { a = {(const char*)y2, HD, HD, 1, nullptr, 0, 0, HD}; W = (const short*)(ws + O_WP1); bias = bp1; }
    else if (mode == 1) { a = {ws + O_P1B, FD, FD, 0, nullptr, 0, 0, FD};      W = (const short*)(ws + O_WP2); bias = bp2; }
    else if (mode == 3) { a = {(const char*)y1, LD, LD, 1, (const char*)y2, HD, 1, KR}; W = (const short*)(ws + O_WR1); bias = br1; }
    else                { a = {ws + O_P1B, FD, FD, 0, nullptr, 0, 0, FD};      W = (const short*)(ws + O_WR2); bias = br2; }
    f32x4 acc[2][4];
    for (int i=0;i<2;++i) for (int j=0;j<4;++j) acc[i][j] = z4();
    const int ke = (a.K + 63) & ~63;
    run_gemm<4>(sm, a, W, a.K, m0, n0, FD, acc, 0, ke);
    unsigned short* outp = (unsigned short*)(ws + ((mode == 0 || mode == 3) ? O_P1B : O_P2B));
    epi_generic<4>(acc, m0, n0, FD, bias, 1, nullptr, 0, outp, FD);
  }
}

__global__ void k_r3(char* ws, const float* br3, float* y7) {
  __shared__ float w3[200];
  for (int i = threadIdx.x; i < 200; i += 256) w3[i] = bf2f(((unsigned short*)(ws + O_WR3))[i]);
  __syncthreads();
  const int m = blockIdx.x * 256 + threadIdx.x;
  const unsigned short* r2 = (const unsigned short*)(ws + O_P2B) + (size_t)m * FD;
  float s = br3[0];
  for (int k = 0; k < FD; k += 8) {
    short8 v = *(const short8*)(r2 + k);
    #pragma unroll
    for (int j = 0; j < 8; ++j) s += bf2f((unsigned short)v[j]) * w3[k + j];
  }
  y7[m] = s;
}

// ---------------- host launcher ----------------
extern "C" void kernel_launch(void* const* d_in, const int* in_sizes, int n_in,
                              void* d_out, int out_size, void* d_ws, size_t ws_size,
                              hipStream_t stream) {
  (void)in_sizes; (void)n_in; (void)out_size; (void)ws_size;
  char* ws = (char*)d_ws;
  #define FIN(i) ((const float*)d_in[i])
  float* out = (float*)d_out;
  float* y0 = out + Y0; float* y1 = out + Y1; float* y2 = out + Y2; float* y3 = out + Y3;
  float* y4 = out + Y4; float* y5 = out + Y5; float* y6 = out + Y6; float* y7 = out + Y7;

  k_init<<<2048, 256, 0, stream>>>(ws, FIN(0), FIN(1), FIN(6), FIN(8), FIN(10),
    FIN(12), FIN(14), FIN(16), FIN(18), FIN(20), FIN(22), FIN(24), FIN(26),
    FIN(28), FIN(30), FIN(32), FIN(17), FIN(19), FIN(25), FIN(27));

  CArgs ca;
  ca.ws = ws; ca.enc = FIN(2); ca.act = FIN(3); ca.nq = FIN(5);
  ca.b_e = FIN(7); ca.b_ih = FIN(9); ca.b_hh = FIN(11); ca.b_q1 = FIN(21); ca.b_q2 = FIN(23);
  ca.y1 = y1; ca.y2 = y2; ca.y5 = y5; ca.y6 = y6;

  k_step1<<<448, 256, 0, stream>>>(ca, 0);     // prologue: gh(0) + emb(0)
  for (int t = 0; t < TS; ++t) {
    k_gi  <<<512, 256, 0, stream>>>(ca, t);    // gi + fused gates -> h(t), y2
    k_mid <<<416, 256, 0, stream>>>(ca, t);    // q1(t) [split-K 4] || gh(t+1)
    k_q2h <<<16,  256, 0, stream>>>(ca, t);    // fused q2 + heads -> post(t), y1,y5,y6
    if (t + 1 < TS) k_emb<<<64, 256, 0, stream>>>(ca, t + 1);  // emb(t+1)
  }

  k_big<<<2048, 256, 0, stream>>>(0, ws, y1, y2, y0, y3, y4, FIN(4), FIN(13), FIN(15), FIN(29), FIN(31));
  k_big<<<2048, 256, 0, stream>>>(1, ws, y1, y2, y0, y3, y4, FIN(4), FIN(13), FIN(15), FIN(29), FIN(31));
  k_big<<<2048, 256, 0, stream>>>(2, ws, y1, y2, y0, y3, y4, FIN(4), FIN(13), FIN(15), FIN(29), FIN(31));
  k_big<<<2048, 256, 0, stream>>>(3, ws, y1, y2, y0, y3, y4, FIN(4), FIN(13), FIN(15), FIN(29), FIN(31));
  k_big<<<2048, 256, 0, stream>>>(4, ws, y1, y2, y0, y3, y4, FIN(4), FIN(13), FIN(15), FIN(29), FIN(31));
  k_r3<<<128, 256, 0, stream>>>(ws, FIN(33), y7);
}